// Round 1
// baseline (546.861 us; speedup 1.0000x reference)
//
#include <hip/hip_runtime.h>

// Problem constants
#define NN    10000
#define EE    160000
#define FIN   512
#define NH    8
#define C1    30
#define HC1   240   // NH*C1
#define C2    64
#define HC2   512   // NH*C2
#define NCLS  64

// ---------------- CSR build ----------------

__global__ __launch_bounds__(256) void hist_kernel(const int* __restrict__ dst,
                                                   int* __restrict__ counts, int E) {
    int e = blockIdx.x * blockDim.x + threadIdx.x;
    if (e < E) atomicAdd(&counts[dst[e]], 1);
}

__global__ __launch_bounds__(256) void scan_kernel(const int* __restrict__ counts,
                                                   int* __restrict__ row_start, int n) {
    __shared__ int sums[256];
    int t = threadIdx.x;
    const int chunk = (n + 255) / 256;
    int beg = t * chunk;
    int end = min(beg + chunk, n);
    int s = 0;
    for (int i = beg; i < end && i < n; ++i) s += counts[i];
    sums[t] = s;
    __syncthreads();
    for (int off = 1; off < 256; off <<= 1) {
        int v = (t >= off) ? sums[t - off] : 0;
        __syncthreads();
        sums[t] += v;
        __syncthreads();
    }
    int run = (t == 0) ? 0 : sums[t - 1];
    for (int i = beg; i < end && i < n; ++i) {
        row_start[i] = run;
        run += counts[i];
    }
    if (t == 255) row_start[n] = sums[255];
}

__global__ __launch_bounds__(256) void scatter_kernel(const int* __restrict__ src,
                                                      const int* __restrict__ dst,
                                                      const int* __restrict__ row_start,
                                                      int* __restrict__ cursor,
                                                      int* __restrict__ edge_src, int E) {
    int e = blockIdx.x * blockDim.x + threadIdx.x;
    if (e < E) {
        int d = dst[e];
        int pos = row_start[d] + atomicAdd(&cursor[d], 1);
        edge_src[pos] = src[e];
    }
}

// ---------------- generic fp32 GEMM: C = A[MxK] * B[KxN] (+bias) ----------------

#define BM 64
#define BN 64
#define BK 16

__global__ __launch_bounds__(256) void gemm_kernel(const float* __restrict__ A,
                                                   const float* __restrict__ B,
                                                   const float* __restrict__ bias,
                                                   float* __restrict__ Cout,
                                                   int M, int Nn, int K) {
    __shared__ float As[BK][BM + 1];
    __shared__ float Bs[BK][BN + 1];
    const int bm = blockIdx.x * BM;
    const int bn = blockIdx.y * BN;
    const int t  = threadIdx.x;
    const int tx = t & 15;
    const int ty = t >> 4;
    float acc[4][4] = {};

    for (int k0 = 0; k0 < K; k0 += BK) {
        #pragma unroll
        for (int i = 0; i < 4; ++i) {
            int l  = t + 256 * i;
            int m  = l >> 4, kk = l & 15;
            int gm = bm + m, gk = k0 + kk;
            float v = 0.f;
            if (gm < M && gk < K) v = A[(long)gm * K + gk];
            As[kk][m] = v;
        }
        #pragma unroll
        for (int i = 0; i < 4; ++i) {
            int l  = t + 256 * i;
            int kk = l >> 6, nn = l & 63;
            int gk = k0 + kk, gn = bn + nn;
            float v = 0.f;
            if (gk < K && gn < Nn) v = B[(long)gk * Nn + gn];
            Bs[kk][nn] = v;
        }
        __syncthreads();
        #pragma unroll
        for (int kk = 0; kk < BK; ++kk) {
            float a[4], b[4];
            #pragma unroll
            for (int r = 0; r < 4; ++r) a[r] = As[kk][ty * 4 + r];
            #pragma unroll
            for (int c = 0; c < 4; ++c) b[c] = Bs[kk][tx * 4 + c];
            #pragma unroll
            for (int r = 0; r < 4; ++r)
                #pragma unroll
                for (int c = 0; c < 4; ++c)
                    acc[r][c] += a[r] * b[c];
        }
        __syncthreads();
    }

    #pragma unroll
    for (int r = 0; r < 4; ++r) {
        int gm = bm + ty * 4 + r;
        if (gm >= M) continue;
        #pragma unroll
        for (int c = 0; c < 4; ++c) {
            int gn = bn + tx * 4 + c;
            if (gn < Nn) {
                float v = acc[r][c];
                if (bias) v += bias[gn];
                Cout[(long)gm * Nn + gn] = v;
            }
        }
    }
}

// ---------------- attention coefficients: asrc/adst [N, NH] ----------------

template <int C>
__global__ __launch_bounds__(256) void att_kernel(const float* __restrict__ hpre,
                                                  const float* __restrict__ a_src,
                                                  const float* __restrict__ a_dst,
                                                  float* __restrict__ asrc,
                                                  float* __restrict__ adst, int n) {
    int idx = blockIdx.x * blockDim.x + threadIdx.x;
    if (idx >= n * NH) return;
    int node = idx >> 3, h = idx & 7;
    const float* row = hpre + (long)node * (NH * C) + h * C;
    float s1 = 0.f, s2 = 0.f;
    #pragma unroll 4
    for (int i = 0; i < C; ++i) {
        float v = row[i];
        s1 += v * a_src[h * C + i];
        s2 += v * a_dst[h * C + i];
    }
    asrc[idx] = s1;
    adst[idx] = s2;
}

// ---------------- per-dst-node softmax aggregation (1 wave / node) ----------------

template <int C, int HC, bool ELU>
__global__ __launch_bounds__(256) void agg_kernel(const float* __restrict__ hpre,  // [N, HC]
                                                  const float* __restrict__ asrc,  // [N, NH]
                                                  const float* __restrict__ adst,  // [N, NH]
                                                  const int* __restrict__ row_start,
                                                  const int* __restrict__ edge_src,
                                                  const float* __restrict__ bias,  // [HC]
                                                  float* __restrict__ out,         // [N, HC]
                                                  int n) {
    const int wave = (blockIdx.x * blockDim.x + threadIdx.x) >> 6;
    const int lane = threadIdx.x & 63;
    if (wave >= n) return;
    const int d   = wave;
    const int beg = row_start[d];
    const int end = row_start[d + 1];

    float adst_h = 0.f;
    if (lane < NH) adst_h = adst[d * NH + lane];

    // Pass A: online softmax stats per head on lanes 0..7 (self loop first)
    float m = 0.f, s = 0.f;
    if (lane < NH) {
        float a = asrc[d * NH + lane] + adst_h;
        a = (a >= 0.f) ? a : 0.2f * a;
        m = a;
        s = 1.f;
    }
    for (int e = beg; e < end; ++e) {
        int srcn = edge_src[e];
        if (lane < NH) {
            float a = asrc[srcn * NH + lane] + adst_h;
            a = (a >= 0.f) ? a : 0.2f * a;
            float mn = fmaxf(m, a);
            s = s * __expf(m - mn) + __expf(a - mn);
            m = mn;
        }
    }
    const float inv_s = 1.f / (s + 1e-16f);

    constexpr int CPL = (HC + 63) / 64;  // channels per lane
    float acc[CPL];
    #pragma unroll
    for (int j = 0; j < CPL; ++j) acc[j] = 0.f;

    // Pass B: weighted accumulation. Self loop:
    {
        float w8 = 0.f;
        if (lane < NH) {
            float a = asrc[d * NH + lane] + adst_h;
            a = (a >= 0.f) ? a : 0.2f * a;
            w8 = __expf(a - m) * inv_s;
        }
        const float* row = hpre + (long)d * HC;
        #pragma unroll
        for (int j = 0; j < CPL; ++j) {
            int c = lane + 64 * j;
            if (c < HC) {
                int h = c / C;
                float w = __shfl(w8, h);
                acc[j] += w * row[c];
            }
        }
    }
    for (int e = beg; e < end; ++e) {
        int srcn = edge_src[e];
        float w8 = 0.f;
        if (lane < NH) {
            float a = asrc[srcn * NH + lane] + adst_h;
            a = (a >= 0.f) ? a : 0.2f * a;
            w8 = __expf(a - m) * inv_s;
        }
        const float* row = hpre + (long)srcn * HC;
        #pragma unroll
        for (int j = 0; j < CPL; ++j) {
            int c = lane + 64 * j;
            if (c < HC) {
                int h = c / C;
                float w = __shfl(w8, h);
                acc[j] += w * row[c];
            }
        }
    }

    #pragma unroll
    for (int j = 0; j < CPL; ++j) {
        int c = lane + 64 * j;
        if (c < HC) {
            float v = acc[j] + bias[c];
            if (ELU) v = (v > 0.f) ? v : __expf(v) - 1.f;
            out[(long)d * HC + c] = v;
        }
    }
}

// ---------------- launch ----------------

extern "C" void kernel_launch(void* const* d_in, const int* in_sizes, int n_in,
                              void* d_out, int out_size, void* d_ws, size_t ws_size,
                              hipStream_t stream) {
    const float* x      = (const float*)d_in[0];
    const int*   eidx   = (const int*)d_in[1];   // [2, E] int32
    const float* W1     = (const float*)d_in[2];
    const float* a1_src = (const float*)d_in[3];
    const float* a1_dst = (const float*)d_in[4];
    const float* b1     = (const float*)d_in[5];
    const float* W2     = (const float*)d_in[6];
    const float* a2_src = (const float*)d_in[7];
    const float* a2_dst = (const float*)d_in[8];
    const float* b2     = (const float*)d_in[9];
    const float* Wlin   = (const float*)d_in[10];
    const float* blin   = (const float*)d_in[11];

    const int* src = eidx;        // row 0
    const int* dst = eidx + EE;   // row 1

    float* out0  = (float*)d_out;                 // [N, NCLS]
    float* h_out = (float*)d_out + (long)NN * NCLS;  // [N, HC2] (output 1)

    // workspace layout (floats then ints)
    float* f = (float*)d_ws;
    float* h1p   = f;                       // 2.4M
    float* h1    = h1p + (long)NN * HC1;    // 2.4M
    float* h2p   = h1 + (long)NN * HC1;     // 5.12M
    float* asrc1 = h2p + (long)NN * HC2;
    float* adst1 = asrc1 + NN * NH;
    float* asrc2 = adst1 + NN * NH;
    float* adst2 = asrc2 + NN * NH;
    int* iws       = (int*)(adst2 + NN * NH);
    int* counts    = iws;
    int* cursor    = counts + NN;
    int* row_start = cursor + NN;          // N+1
    int* edge_src  = row_start + NN + 1;   // E

    // zero counts + cursor
    hipMemsetAsync(counts, 0, 2 * NN * sizeof(int), stream);

    // CSR by dst
    hist_kernel<<<(EE + 255) / 256, 256, 0, stream>>>(dst, counts, EE);
    scan_kernel<<<1, 256, 0, stream>>>(counts, row_start, NN);
    scatter_kernel<<<(EE + 255) / 256, 256, 0, stream>>>(src, dst, row_start, cursor,
                                                         edge_src, EE);

    // Layer 1: h1p = x @ W1
    {
        dim3 grid((NN + BM - 1) / BM, (HC1 + BN - 1) / BN);
        gemm_kernel<<<grid, 256, 0, stream>>>(x, W1, nullptr, h1p, NN, HC1, FIN);
    }
    att_kernel<C1><<<(NN * NH + 255) / 256, 256, 0, stream>>>(h1p, a1_src, a1_dst,
                                                              asrc1, adst1, NN);
    agg_kernel<C1, HC1, true><<<(NN + 3) / 4, 256, 0, stream>>>(
        h1p, asrc1, adst1, row_start, edge_src, b1, h1, NN);

    // Layer 2: h2p = h1 @ W2
    {
        dim3 grid((NN + BM - 1) / BM, (HC2 + BN - 1) / BN);
        gemm_kernel<<<grid, 256, 0, stream>>>(h1, W2, nullptr, h2p, NN, HC2, HC1);
    }
    att_kernel<C2><<<(NN * NH + 255) / 256, 256, 0, stream>>>(h2p, a2_src, a2_dst,
                                                              asrc2, adst2, NN);
    agg_kernel<C2, HC2, false><<<(NN + 3) / 4, 256, 0, stream>>>(
        h2p, asrc2, adst2, row_start, edge_src, b2, h_out, NN);

    // Head: out0 = h_out @ Wlin + blin
    {
        dim3 grid((NN + BM - 1) / BM, (NCLS + BN - 1) / BN);
        gemm_kernel<<<grid, 256, 0, stream>>>(h_out, Wlin, blin, out0, NN, NCLS, FIN);
    }
}

// Round 2
// 421.565 us; speedup vs baseline: 1.2972x; 1.2972x over previous
//
#include <hip/hip_runtime.h>

// Problem constants
#define NN    10000
#define EE    160000
#define FIN   512
#define NH    8
#define C1    30
#define HC1   240   // NH*C1
#define C2    64
#define HC2   512   // NH*C2
#define NCLS  64

// ---------------- CSR build ----------------

__global__ __launch_bounds__(256) void hist_kernel(const int* __restrict__ dst,
                                                   int* __restrict__ counts, int E) {
    int e = blockIdx.x * blockDim.x + threadIdx.x;
    if (e < E) atomicAdd(&counts[dst[e]], 1);
}

__global__ __launch_bounds__(256) void scan_kernel(const int* __restrict__ counts,
                                                   int* __restrict__ row_start, int n) {
    __shared__ int sums[256];
    int t = threadIdx.x;
    const int chunk = (n + 255) / 256;
    int beg = t * chunk;
    int end = min(beg + chunk, n);
    int s = 0;
    for (int i = beg; i < end && i < n; ++i) s += counts[i];
    sums[t] = s;
    __syncthreads();
    for (int off = 1; off < 256; off <<= 1) {
        int v = (t >= off) ? sums[t - off] : 0;
        __syncthreads();
        sums[t] += v;
        __syncthreads();
    }
    int run = (t == 0) ? 0 : sums[t - 1];
    for (int i = beg; i < end && i < n; ++i) {
        row_start[i] = run;
        run += counts[i];
    }
    if (t == 255) row_start[n] = sums[255];
}

__global__ __launch_bounds__(256) void scatter_kernel(const int* __restrict__ src,
                                                      const int* __restrict__ dst,
                                                      const int* __restrict__ row_start,
                                                      int* __restrict__ cursor,
                                                      int* __restrict__ edge_src, int E) {
    int e = blockIdx.x * blockDim.x + threadIdx.x;
    if (e < E) {
        int d = dst[e];
        int pos = row_start[d] + atomicAdd(&cursor[d], 1);
        edge_src[pos] = src[e];
    }
}

// ---------------- fp32 GEMM: C = A[MxK] * B[KxN] (+bias) ----------------
// BN=64 fixed, BK=16 fixed, 256 threads. Per-thread tile TM x 4.
// Requires K % 16 == 0 (holds: 512, 240).

template <int BM, int TM>
__global__ __launch_bounds__(256) void gemm_f32(const float* __restrict__ A,
                                                const float* __restrict__ B,
                                                const float* __restrict__ bias,
                                                float* __restrict__ Cout,
                                                int M, int Nn, int K) {
    constexpr int BN = 64;
    constexpr int BK = 16;
    __shared__ float As[BK][BM + 4];   // +4 keeps 16B row alignment
    __shared__ float Bs[BK][BN + 4];
    const int t  = threadIdx.x;
    const int tx = t & 15;    // 16 col-groups x 4 cols
    const int ty = t >> 4;    // 16 row-groups x TM rows
    const int bm = blockIdx.x * BM;
    const int bn = blockIdx.y * BN;

    float acc[TM][4];
    #pragma unroll
    for (int r = 0; r < TM; ++r)
        #pragma unroll
        for (int c = 0; c < 4; ++c) acc[r][c] = 0.f;

    for (int k0 = 0; k0 < K; k0 += BK) {
        // stage A tile (BM x BK) via float4 along K
        constexpr int NA4 = BM * BK / 4;
        #pragma unroll
        for (int idx = t; idx < NA4; idx += 256) {
            int row = idx >> 2;       // 0..BM-1
            int c4  = idx & 3;        // which 4-k chunk
            int gm = bm + row;
            float4 v = make_float4(0.f, 0.f, 0.f, 0.f);
            if (gm < M) v = *(const float4*)(A + (size_t)gm * K + k0 + 4 * c4);
            As[4 * c4 + 0][row] = v.x;
            As[4 * c4 + 1][row] = v.y;
            As[4 * c4 + 2][row] = v.z;
            As[4 * c4 + 3][row] = v.w;
        }
        // stage B tile (BK x BN): 16 rows x 16 float4 = 256 threads
        {
            int kb = t >> 4;
            int n4 = t & 15;
            int gk = k0 + kb;
            int gn = bn + 4 * n4;
            float4 v = make_float4(0.f, 0.f, 0.f, 0.f);
            const float* Brow = B + (size_t)gk * Nn;
            if (gn + 3 < Nn) {
                v = *(const float4*)(Brow + gn);
            } else {
                if (gn + 0 < Nn) v.x = Brow[gn + 0];
                if (gn + 1 < Nn) v.y = Brow[gn + 1];
                if (gn + 2 < Nn) v.z = Brow[gn + 2];
                if (gn + 3 < Nn) v.w = Brow[gn + 3];
            }
            *(float4*)&Bs[kb][4 * n4] = v;
        }
        __syncthreads();

        #pragma unroll
        for (int kk = 0; kk < BK; ++kk) {
            float a[TM];
            if constexpr (TM % 4 == 0) {
                #pragma unroll
                for (int r4 = 0; r4 < TM / 4; ++r4) {
                    float4 av = *(const float4*)&As[kk][ty * TM + 4 * r4];
                    a[4 * r4 + 0] = av.x;
                    a[4 * r4 + 1] = av.y;
                    a[4 * r4 + 2] = av.z;
                    a[4 * r4 + 3] = av.w;
                }
            } else {
                #pragma unroll
                for (int r = 0; r < TM; ++r) a[r] = As[kk][ty * TM + r];
            }
            float4 bv = *(const float4*)&Bs[kk][tx * 4];
            float b[4] = {bv.x, bv.y, bv.z, bv.w};
            #pragma unroll
            for (int r = 0; r < TM; ++r)
                #pragma unroll
                for (int c = 0; c < 4; ++c)
                    acc[r][c] += a[r] * b[c];
        }
        __syncthreads();
    }

    #pragma unroll
    for (int r = 0; r < TM; ++r) {
        int gm = bm + ty * TM + r;
        if (gm >= M) continue;
        #pragma unroll
        for (int c = 0; c < 4; ++c) {
            int gn = bn + tx * 4 + c;
            if (gn < Nn) {
                float v = acc[r][c];
                if (bias) v += bias[gn];
                Cout[(size_t)gm * Nn + gn] = v;
            }
        }
    }
}

// ---------------- attention coefficients: asrc/adst [N, NH] ----------------

template <int C>
__global__ __launch_bounds__(256) void att_kernel(const float* __restrict__ hpre,
                                                  const float* __restrict__ a_src,
                                                  const float* __restrict__ a_dst,
                                                  float* __restrict__ asrc,
                                                  float* __restrict__ adst, int n) {
    int idx = blockIdx.x * blockDim.x + threadIdx.x;
    if (idx >= n * NH) return;
    int node = idx >> 3, h = idx & 7;
    const float* row = hpre + (size_t)node * (NH * C) + h * C;
    float s1 = 0.f, s2 = 0.f;
    #pragma unroll 4
    for (int i = 0; i < C; ++i) {
        float v = row[i];
        s1 += v * a_src[h * C + i];
        s2 += v * a_dst[h * C + i];
    }
    asrc[idx] = s1;
    adst[idx] = s2;
}

// ---------------- per-dst-node softmax aggregation (1 wave / node) ----------------

template <int C, int HC, bool ELU>
__global__ __launch_bounds__(256) void agg_kernel(const float* __restrict__ hpre,  // [N, HC]
                                                  const float* __restrict__ asrc,  // [N, NH]
                                                  const float* __restrict__ adst,  // [N, NH]
                                                  const int* __restrict__ row_start,
                                                  const int* __restrict__ edge_src,
                                                  const float* __restrict__ bias,  // [HC]
                                                  float* __restrict__ out,         // [N, HC]
                                                  int n) {
    const int wave = (blockIdx.x * blockDim.x + threadIdx.x) >> 6;
    const int lane = threadIdx.x & 63;
    if (wave >= n) return;
    const int d   = wave;
    const int beg = row_start[d];
    const int end = row_start[d + 1];

    float adst_h = (lane < NH) ? adst[d * NH + lane] : 0.f;

    // Pass A: online softmax stats per head on lanes 0..7 (self loop included)
    float m = 0.f, s = 0.f;
    if (lane < NH) {
        float a = asrc[d * NH + lane] + adst_h;
        a = (a >= 0.f) ? a : 0.2f * a;
        m = a;
        s = 1.f;
    }
    for (int e = beg; e < end; ++e) {
        int srcn = edge_src[e];
        if (lane < NH) {
            float a = asrc[srcn * NH + lane] + adst_h;
            a = (a >= 0.f) ? a : 0.2f * a;
            float mn = fmaxf(m, a);
            s = s * __expf(m - mn) + __expf(a - mn);
            m = mn;
        }
    }
    const float inv_s = 1.f / (s + 1e-16f);

    constexpr int NQ = HC / 4;          // float4 per row
    constexpr int NJ = (NQ + 63) / 64;  // float4 slots per lane
    float4 acc[NJ];
    int hq[NJ][4];
    bool val[NJ];
    #pragma unroll
    for (int j = 0; j < NJ; ++j) {
        acc[j] = make_float4(0.f, 0.f, 0.f, 0.f);
        int c4 = lane + 64 * j;
        val[j] = (c4 < NQ);
        int c = 4 * (c4 < NQ ? c4 : 0);
        #pragma unroll
        for (int q = 0; q < 4; ++q) hq[j][q] = (c + q) / C;
    }

    // Pass B: self loop first (e = beg-1 sentinel), then the edges.
    for (int e = beg - 1;;) {
        int srcn = (e < beg) ? d : edge_src[e];
        float w8 = 0.f;
        if (lane < NH) {
            float a = asrc[srcn * NH + lane] + adst_h;
            a = (a >= 0.f) ? a : 0.2f * a;
            w8 = __expf(a - m) * inv_s;
        }
        const float4* row = (const float4*)(hpre + (size_t)srcn * HC);
        #pragma unroll
        for (int j = 0; j < NJ; ++j) {
            if (val[j]) {
                float4 v = row[lane + 64 * j];
                if constexpr (C == 64) {
                    float w = __shfl(w8, hq[j][0]);
                    acc[j].x += w * v.x;
                    acc[j].y += w * v.y;
                    acc[j].z += w * v.z;
                    acc[j].w += w * v.w;
                } else {
                    acc[j].x += __shfl(w8, hq[j][0]) * v.x;
                    acc[j].y += __shfl(w8, hq[j][1]) * v.y;
                    acc[j].z += __shfl(w8, hq[j][2]) * v.z;
                    acc[j].w += __shfl(w8, hq[j][3]) * v.w;
                }
            }
        }
        if (++e >= end) break;
    }

    #pragma unroll
    for (int j = 0; j < NJ; ++j) {
        if (val[j]) {
            int c4 = lane + 64 * j;
            float4 b4 = ((const float4*)bias)[c4];
            float4 v;
            v.x = acc[j].x + b4.x;
            v.y = acc[j].y + b4.y;
            v.z = acc[j].z + b4.z;
            v.w = acc[j].w + b4.w;
            if (ELU) {
                v.x = (v.x > 0.f) ? v.x : __expf(v.x) - 1.f;
                v.y = (v.y > 0.f) ? v.y : __expf(v.y) - 1.f;
                v.z = (v.z > 0.f) ? v.z : __expf(v.z) - 1.f;
                v.w = (v.w > 0.f) ? v.w : __expf(v.w) - 1.f;
            }
            ((float4*)(out + (size_t)d * HC))[c4] = v;
        }
    }
}

// ---------------- launch ----------------

extern "C" void kernel_launch(void* const* d_in, const int* in_sizes, int n_in,
                              void* d_out, int out_size, void* d_ws, size_t ws_size,
                              hipStream_t stream) {
    const float* x      = (const float*)d_in[0];
    const int*   eidx   = (const int*)d_in[1];   // [2, E]
    const float* W1     = (const float*)d_in[2];
    const float* a1_src = (const float*)d_in[3];
    const float* a1_dst = (const float*)d_in[4];
    const float* b1     = (const float*)d_in[5];
    const float* W2     = (const float*)d_in[6];
    const float* a2_src = (const float*)d_in[7];
    const float* a2_dst = (const float*)d_in[8];
    const float* b2     = (const float*)d_in[9];
    const float* Wlin   = (const float*)d_in[10];
    const float* blin   = (const float*)d_in[11];

    const int* src = eidx;        // row 0
    const int* dst = eidx + EE;   // row 1

    float* out0  = (float*)d_out;                    // [N, NCLS]
    float* h_out = (float*)d_out + (size_t)NN * NCLS;  // [N, HC2] (output 1)

    // workspace layout
    float* f = (float*)d_ws;
    float* h1p   = f;                        // N*HC1
    float* h1    = h1p + (size_t)NN * HC1;   // N*HC1
    float* h2p   = h1 + (size_t)NN * HC1;    // N*HC2
    float* asrc1 = h2p + (size_t)NN * HC2;
    float* adst1 = asrc1 + NN * NH;
    float* asrc2 = adst1 + NN * NH;
    float* adst2 = asrc2 + NN * NH;
    int* counts    = (int*)(adst2 + NN * NH);
    int* cursor    = counts + NN;
    int* row_start = cursor + NN;            // N+1
    int* edge_src  = row_start + NN + 1;     // E

    hipMemsetAsync(counts, 0, 2 * NN * sizeof(int), stream);

    // CSR by dst
    hist_kernel<<<(EE + 255) / 256, 256, 0, stream>>>(dst, counts, EE);
    scan_kernel<<<1, 256, 0, stream>>>(counts, row_start, NN);
    scatter_kernel<<<(EE + 255) / 256, 256, 0, stream>>>(src, dst, row_start, cursor,
                                                         edge_src, EE);

    // Layer 1: h1p = x @ W1
    {
        dim3 grid((NN + 127) / 128, (HC1 + 63) / 64);
        gemm_f32<128, 8><<<grid, 256, 0, stream>>>(x, W1, nullptr, h1p, NN, HC1, FIN);
    }
    att_kernel<C1><<<(NN * NH + 255) / 256, 256, 0, stream>>>(h1p, a1_src, a1_dst,
                                                              asrc1, adst1, NN);
    agg_kernel<C1, HC1, true><<<(NN + 3) / 4, 256, 0, stream>>>(
        h1p, asrc1, adst1, row_start, edge_src, b1, h1, NN);

    // Layer 2: h2p = h1 @ W2
    {
        dim3 grid((NN + 127) / 128, (HC2 + 63) / 64);
        gemm_f32<128, 8><<<grid, 256, 0, stream>>>(h1, W2, nullptr, h2p, NN, HC2, HC1);
    }
    att_kernel<C2><<<(NN * NH + 255) / 256, 256, 0, stream>>>(h2p, a2_src, a2_dst,
                                                              asrc2, adst2, NN);
    agg_kernel<C2, HC2, false><<<(NN + 3) / 4, 256, 0, stream>>>(
        h2p, asrc2, adst2, row_start, edge_src, b2, h_out, NN);

    // Head: out0 = h_out @ Wlin + blin  (small N -> BM=32 for grid size)
    {
        dim3 grid((NN + 31) / 32, (NCLS + 63) / 64);
        gemm_f32<32, 2><<<grid, 256, 0, stream>>>(h_out, Wlin, blin, out0, NN, NCLS, HC2);
    }
}

// Round 3
// 373.162 us; speedup vs baseline: 1.4655x; 1.1297x over previous
//
#include <hip/hip_runtime.h>

// Problem constants
#define NN    10000
#define EE    160000
#define FIN   512
#define NH    8
#define C1    30
#define HC1   240   // NH*C1
#define C2    64
#define HC2   512   // NH*C2
#define NCLS  64

// ---------------- CSR build ----------------

__global__ __launch_bounds__(256) void hist_kernel(const int* __restrict__ dst,
                                                   int* __restrict__ counts, int E) {
    int e = blockIdx.x * blockDim.x + threadIdx.x;
    if (e < E) atomicAdd(&counts[dst[e]], 1);
}

__global__ __launch_bounds__(256) void scan_kernel(const int* __restrict__ counts,
                                                   int* __restrict__ row_start, int n) {
    __shared__ int sums[256];
    int t = threadIdx.x;
    const int chunk = (n + 255) / 256;
    int beg = t * chunk;
    int end = min(beg + chunk, n);
    int s = 0;
    for (int i = beg; i < end && i < n; ++i) s += counts[i];
    sums[t] = s;
    __syncthreads();
    for (int off = 1; off < 256; off <<= 1) {
        int v = (t >= off) ? sums[t - off] : 0;
        __syncthreads();
        sums[t] += v;
        __syncthreads();
    }
    int run = (t == 0) ? 0 : sums[t - 1];
    for (int i = beg; i < end && i < n; ++i) {
        row_start[i] = run;
        run += counts[i];
    }
    if (t == 255) row_start[n] = sums[255];
}

__global__ __launch_bounds__(256) void scatter_kernel(const int* __restrict__ src,
                                                      const int* __restrict__ dst,
                                                      const int* __restrict__ row_start,
                                                      int* __restrict__ cursor,
                                                      int* __restrict__ edge_src, int E) {
    int e = blockIdx.x * blockDim.x + threadIdx.x;
    if (e < E) {
        int d = dst[e];
        int pos = row_start[d] + atomicAdd(&cursor[d], 1);
        edge_src[pos] = src[e];
    }
}

// ---------------- fp32 GEMM: C = A[MxK] * B[KxN] (+bias) ----------------

template <int BM, int TM>
__global__ __launch_bounds__(256) void gemm_f32(const float* __restrict__ A,
                                                const float* __restrict__ B,
                                                const float* __restrict__ bias,
                                                float* __restrict__ Cout,
                                                int M, int Nn, int K) {
    constexpr int BN = 64;
    constexpr int BK = 16;
    __shared__ float As[BK][BM + 4];
    __shared__ float Bs[BK][BN + 4];
    const int t  = threadIdx.x;
    const int tx = t & 15;
    const int ty = t >> 4;
    const int bm = blockIdx.x * BM;
    const int bn = blockIdx.y * BN;

    float acc[TM][4];
    #pragma unroll
    for (int r = 0; r < TM; ++r)
        #pragma unroll
        for (int c = 0; c < 4; ++c) acc[r][c] = 0.f;

    for (int k0 = 0; k0 < K; k0 += BK) {
        constexpr int NA4 = BM * BK / 4;
        #pragma unroll
        for (int idx = t; idx < NA4; idx += 256) {
            int row = idx >> 2;
            int c4  = idx & 3;
            int gm = bm + row;
            float4 v = make_float4(0.f, 0.f, 0.f, 0.f);
            if (gm < M) v = *(const float4*)(A + (size_t)gm * K + k0 + 4 * c4);
            As[4 * c4 + 0][row] = v.x;
            As[4 * c4 + 1][row] = v.y;
            As[4 * c4 + 2][row] = v.z;
            As[4 * c4 + 3][row] = v.w;
        }
        {
            int kb = t >> 4;
            int n4 = t & 15;
            int gk = k0 + kb;
            int gn = bn + 4 * n4;
            float4 v = make_float4(0.f, 0.f, 0.f, 0.f);
            const float* Brow = B + (size_t)gk * Nn;
            if (gn + 3 < Nn) {
                v = *(const float4*)(Brow + gn);
            } else {
                if (gn + 0 < Nn) v.x = Brow[gn + 0];
                if (gn + 1 < Nn) v.y = Brow[gn + 1];
                if (gn + 2 < Nn) v.z = Brow[gn + 2];
                if (gn + 3 < Nn) v.w = Brow[gn + 3];
            }
            *(float4*)&Bs[kb][4 * n4] = v;
        }
        __syncthreads();

        #pragma unroll
        for (int kk = 0; kk < BK; ++kk) {
            float a[TM];
            if constexpr (TM % 4 == 0) {
                #pragma unroll
                for (int r4 = 0; r4 < TM / 4; ++r4) {
                    float4 av = *(const float4*)&As[kk][ty * TM + 4 * r4];
                    a[4 * r4 + 0] = av.x;
                    a[4 * r4 + 1] = av.y;
                    a[4 * r4 + 2] = av.z;
                    a[4 * r4 + 3] = av.w;
                }
            } else {
                #pragma unroll
                for (int r = 0; r < TM; ++r) a[r] = As[kk][ty * TM + r];
            }
            float4 bv = *(const float4*)&Bs[kk][tx * 4];
            float b[4] = {bv.x, bv.y, bv.z, bv.w};
            #pragma unroll
            for (int r = 0; r < TM; ++r)
                #pragma unroll
                for (int c = 0; c < 4; ++c)
                    acc[r][c] += a[r] * b[c];
        }
        __syncthreads();
    }

    #pragma unroll
    for (int r = 0; r < TM; ++r) {
        int gm = bm + ty * TM + r;
        if (gm >= M) continue;
        #pragma unroll
        for (int c = 0; c < 4; ++c) {
            int gn = bn + tx * 4 + c;
            if (gn < Nn) {
                float v = acc[r][c];
                if (bias) v += bias[gn];
                Cout[(size_t)gm * Nn + gn] = v;
            }
        }
    }
}

// ---------------- attention coefficients: asrc/adst [N, NH] ----------------

template <int C>
__global__ __launch_bounds__(256) void att_kernel(const float* __restrict__ hpre,
                                                  const float* __restrict__ a_src,
                                                  const float* __restrict__ a_dst,
                                                  float* __restrict__ asrc,
                                                  float* __restrict__ adst, int n) {
    int idx = blockIdx.x * blockDim.x + threadIdx.x;
    if (idx >= n * NH) return;
    int node = idx >> 3, h = idx & 7;
    const float* row = hpre + (size_t)node * (NH * C) + h * C;
    float s1 = 0.f, s2 = 0.f;
    #pragma unroll 4
    for (int i = 0; i < C; ++i) {
        float v = row[i];
        s1 += v * a_src[h * C + i];
        s2 += v * a_dst[h * C + i];
    }
    asrc[idx] = s1;
    adst[idx] = s2;
}

// ---------------- fused single-pass softmax aggregation ----------------
// SPLIT waves per dst node; each wave owns 64 float4 channels (1 float4/lane).
// Online softmax with running rescale; normalize by s at the end.

template <int C, int HC, int SPLIT, bool ELU>
__global__ __launch_bounds__(256) void agg_kernel(const float* __restrict__ hpre,  // [N, HC]
                                                  const float* __restrict__ asrc,  // [N, NH]
                                                  const float* __restrict__ adst,  // [N, NH]
                                                  const int* __restrict__ row_start,
                                                  const int* __restrict__ edge_src,
                                                  const float* __restrict__ bias,  // [HC]
                                                  float* __restrict__ out,         // [N, HC]
                                                  int n) {
    constexpr int NQ = HC / 4;  // total float4 per row; NQ <= SPLIT*64 required
    const int gw   = (blockIdx.x * blockDim.x + threadIdx.x) >> 6;
    const int lane = threadIdx.x & 63;
    const int d    = gw / SPLIT;
    const int part = gw % SPLIT;
    if (d >= n) return;

    const int c4   = part * 64 + lane;   // this lane's float4 index
    const bool have = (c4 < NQ);
    const int c4c  = have ? c4 : 0;
    int hq[4];
    #pragma unroll
    for (int q = 0; q < 4; ++q) hq[q] = (4 * c4c + q) / C;

    const int beg = row_start[d];
    const int end = row_start[d + 1];

    const float adst_h = (lane < NH) ? adst[d * NH + lane] : 0.f;

    // self loop init: weight exp(0)=1
    float m, s;
    float4 acc;
    {
        float a = (lane < NH) ? asrc[d * NH + lane] + adst_h : 0.f;
        a = fmaxf(a, 0.2f * a);  // leaky_relu(a, 0.2)
        m = a;
        s = 1.f;
        const float4* row = (const float4*)(hpre + (size_t)d * HC);
        acc = have ? row[c4] : make_float4(0.f, 0.f, 0.f, 0.f);
    }

    int e = beg;
    for (; e + 1 < end; e += 2) {
        int s1 = edge_src[e];
        int s2 = edge_src[e + 1];
        const float4* r1 = (const float4*)(hpre + (size_t)s1 * HC);
        const float4* r2 = (const float4*)(hpre + (size_t)s2 * HC);
        float4 v1 = have ? r1[c4] : make_float4(0.f, 0.f, 0.f, 0.f);
        float4 v2 = have ? r2[c4] : make_float4(0.f, 0.f, 0.f, 0.f);
        float a1 = 0.f, a2 = 0.f;
        if (lane < NH) {
            a1 = asrc[s1 * NH + lane] + adst_h;
            a2 = asrc[s2 * NH + lane] + adst_h;
        }
        a1 = fmaxf(a1, 0.2f * a1);
        a2 = fmaxf(a2, 0.2f * a2);
        float mn = fmaxf(m, fmaxf(a1, a2));
        float al = __expf(m - mn);
        float w1 = __expf(a1 - mn);
        float w2 = __expf(a2 - mn);
        s = s * al + w1 + w2;
        m = mn;
        if constexpr (C == 64) {
            int h = c4c >> 4;
            float alc = __shfl(al, h);
            float w1c = __shfl(w1, h);
            float w2c = __shfl(w2, h);
            acc.x = acc.x * alc + w1c * v1.x + w2c * v2.x;
            acc.y = acc.y * alc + w1c * v1.y + w2c * v2.y;
            acc.z = acc.z * alc + w1c * v1.z + w2c * v2.z;
            acc.w = acc.w * alc + w1c * v1.w + w2c * v2.w;
        } else {
            acc.x = acc.x * __shfl(al, hq[0]) + __shfl(w1, hq[0]) * v1.x + __shfl(w2, hq[0]) * v2.x;
            acc.y = acc.y * __shfl(al, hq[1]) + __shfl(w1, hq[1]) * v1.y + __shfl(w2, hq[1]) * v2.y;
            acc.z = acc.z * __shfl(al, hq[2]) + __shfl(w1, hq[2]) * v1.z + __shfl(w2, hq[2]) * v2.z;
            acc.w = acc.w * __shfl(al, hq[3]) + __shfl(w1, hq[3]) * v1.w + __shfl(w2, hq[3]) * v2.w;
        }
    }
    if (e < end) {  // leftover single edge
        int s1 = edge_src[e];
        const float4* r1 = (const float4*)(hpre + (size_t)s1 * HC);
        float4 v1 = have ? r1[c4] : make_float4(0.f, 0.f, 0.f, 0.f);
        float a1 = 0.f;
        if (lane < NH) a1 = asrc[s1 * NH + lane] + adst_h;
        a1 = fmaxf(a1, 0.2f * a1);
        float mn = fmaxf(m, a1);
        float al = __expf(m - mn);
        float w1 = __expf(a1 - mn);
        s = s * al + w1;
        m = mn;
        if constexpr (C == 64) {
            int h = c4c >> 4;
            float alc = __shfl(al, h);
            float w1c = __shfl(w1, h);
            acc.x = acc.x * alc + w1c * v1.x;
            acc.y = acc.y * alc + w1c * v1.y;
            acc.z = acc.z * alc + w1c * v1.z;
            acc.w = acc.w * alc + w1c * v1.w;
        } else {
            acc.x = acc.x * __shfl(al, hq[0]) + __shfl(w1, hq[0]) * v1.x;
            acc.y = acc.y * __shfl(al, hq[1]) + __shfl(w1, hq[1]) * v1.y;
            acc.z = acc.z * __shfl(al, hq[2]) + __shfl(w1, hq[2]) * v1.z;
            acc.w = acc.w * __shfl(al, hq[3]) + __shfl(w1, hq[3]) * v1.w;
        }
    }

    // normalize per head, add bias, optional ELU, store
    float inv = 1.f / s;  // valid on lanes 0..7
    if (have) {
        float4 b4 = ((const float4*)bias)[c4];
        float4 v;
        if constexpr (C == 64) {
            float ivc = __shfl(inv, c4c >> 4);
            v.x = acc.x * ivc + b4.x;
            v.y = acc.y * ivc + b4.y;
            v.z = acc.z * ivc + b4.z;
            v.w = acc.w * ivc + b4.w;
        } else {
            v.x = acc.x * __shfl(inv, hq[0]) + b4.x;
            v.y = acc.y * __shfl(inv, hq[1]) + b4.y;
            v.z = acc.z * __shfl(inv, hq[2]) + b4.z;
            v.w = acc.w * __shfl(inv, hq[3]) + b4.w;
        }
        if (ELU) {
            v.x = (v.x > 0.f) ? v.x : __expf(v.x) - 1.f;
            v.y = (v.y > 0.f) ? v.y : __expf(v.y) - 1.f;
            v.z = (v.z > 0.f) ? v.z : __expf(v.z) - 1.f;
            v.w = (v.w > 0.f) ? v.w : __expf(v.w) - 1.f;
        }
        ((float4*)(out + (size_t)d * HC))[c4] = v;
    }
}

// ---------------- launch ----------------

extern "C" void kernel_launch(void* const* d_in, const int* in_sizes, int n_in,
                              void* d_out, int out_size, void* d_ws, size_t ws_size,
                              hipStream_t stream) {
    const float* x      = (const float*)d_in[0];
    const int*   eidx   = (const int*)d_in[1];   // [2, E]
    const float* W1     = (const float*)d_in[2];
    const float* a1_src = (const float*)d_in[3];
    const float* a1_dst = (const float*)d_in[4];
    const float* b1     = (const float*)d_in[5];
    const float* W2     = (const float*)d_in[6];
    const float* a2_src = (const float*)d_in[7];
    const float* a2_dst = (const float*)d_in[8];
    const float* b2     = (const float*)d_in[9];
    const float* Wlin   = (const float*)d_in[10];
    const float* blin   = (const float*)d_in[11];

    const int* src = eidx;        // row 0
    const int* dst = eidx + EE;   // row 1

    float* out0  = (float*)d_out;                      // [N, NCLS]
    float* h_out = (float*)d_out + (size_t)NN * NCLS;  // [N, HC2] (output 1)

    // workspace layout
    float* f = (float*)d_ws;
    float* h1p   = f;
    float* h1    = h1p + (size_t)NN * HC1;
    float* h2p   = h1 + (size_t)NN * HC1;
    float* asrc1 = h2p + (size_t)NN * HC2;
    float* adst1 = asrc1 + NN * NH;
    float* asrc2 = adst1 + NN * NH;
    float* adst2 = asrc2 + NN * NH;
    int* counts    = (int*)(adst2 + NN * NH);
    int* cursor    = counts + NN;
    int* row_start = cursor + NN;            // N+1
    int* edge_src  = row_start + NN + 1;     // E

    hipMemsetAsync(counts, 0, 2 * NN * sizeof(int), stream);

    // CSR by dst
    hist_kernel<<<(EE + 255) / 256, 256, 0, stream>>>(dst, counts, EE);
    scan_kernel<<<1, 256, 0, stream>>>(counts, row_start, NN);
    scatter_kernel<<<(EE + 255) / 256, 256, 0, stream>>>(src, dst, row_start, cursor,
                                                         edge_src, EE);

    // Layer 1: h1p = x @ W1
    {
        dim3 grid((NN + 127) / 128, (HC1 + 63) / 64);
        gemm_f32<128, 8><<<grid, 256, 0, stream>>>(x, W1, nullptr, h1p, NN, HC1, FIN);
    }
    att_kernel<C1><<<(NN * NH + 255) / 256, 256, 0, stream>>>(h1p, a1_src, a1_dst,
                                                              asrc1, adst1, NN);
    agg_kernel<C1, HC1, 1, true><<<(NN * 1 + 3) / 4, 256, 0, stream>>>(
        h1p, asrc1, adst1, row_start, edge_src, b1, h1, NN);

    // Layer 2: h2p = h1 @ W2
    {
        dim3 grid((NN + 127) / 128, (HC2 + 63) / 64);
        gemm_f32<128, 8><<<grid, 256, 0, stream>>>(h1, W2, nullptr, h2p, NN, HC2, HC1);
    }
    att_kernel<C2><<<(NN * NH + 255) / 256, 256, 0, stream>>>(h2p, a2_src, a2_dst,
                                                              asrc2, adst2, NN);
    agg_kernel<C2, HC2, 2, false><<<(NN * 2 + 3) / 4, 256, 0, stream>>>(
        h2p, asrc2, adst2, row_start, edge_src, b2, h_out, NN);

    // Head: out0 = h_out @ Wlin + blin
    {
        dim3 grid((NN + 31) / 32, (NCLS + 63) / 64);
        gemm_f32<32, 2><<<grid, 256, 0, stream>>>(h_out, Wlin, blin, out0, NN, NCLS, HC2);
    }
}

// Round 4
// 295.057 us; speedup vs baseline: 1.8534x; 1.2647x over previous
//
#include <hip/hip_runtime.h>

typedef unsigned short ushort_t;
typedef float v4f __attribute__((ext_vector_type(4)));
typedef short v8s __attribute__((ext_vector_type(8)));
typedef unsigned short u16x8 __attribute__((ext_vector_type(8)));

// Problem constants
#define NN    10000
#define EE    160000
#define FIN   512
#define NH    8
#define C1    30
#define HC1   240   // NH*C1
#define HC1P  256   // padded
#define C2    64
#define HC2   512   // NH*C2
#define NCLS  64

// ---------------- CSR build ----------------

__global__ __launch_bounds__(256) void hist_kernel(const int* __restrict__ dst,
                                                   int* __restrict__ counts, int E) {
    int e = blockIdx.x * blockDim.x + threadIdx.x;
    if (e < E) atomicAdd(&counts[dst[e]], 1);
}

__global__ __launch_bounds__(256) void scan_kernel(const int* __restrict__ counts,
                                                   int* __restrict__ row_start, int n) {
    __shared__ int sums[256];
    int t = threadIdx.x;
    const int chunk = (n + 255) / 256;
    int beg = t * chunk;
    int end = min(beg + chunk, n);
    int s = 0;
    for (int i = beg; i < end && i < n; ++i) s += counts[i];
    sums[t] = s;
    __syncthreads();
    for (int off = 1; off < 256; off <<= 1) {
        int v = (t >= off) ? sums[t - off] : 0;
        __syncthreads();
        sums[t] += v;
        __syncthreads();
    }
    int run = (t == 0) ? 0 : sums[t - 1];
    for (int i = beg; i < end && i < n; ++i) {
        row_start[i] = run;
        run += counts[i];
    }
    if (t == 255) row_start[n] = sums[255];
}

__global__ __launch_bounds__(256) void scatter_kernel(const int* __restrict__ src,
                                                      const int* __restrict__ dst,
                                                      const int* __restrict__ row_start,
                                                      int* __restrict__ cursor,
                                                      int* __restrict__ edge_src, int E) {
    int e = blockIdx.x * blockDim.x + threadIdx.x;
    if (e < E) {
        int d = dst[e];
        int pos = row_start[d] + atomicAdd(&cursor[d], 1);
        edge_src[pos] = src[e];
    }
}

// ---------------- bf16 hi/lo split helpers ----------------

__device__ __forceinline__ void split1(float v, ushort_t& h, ushort_t& l) {
    unsigned u = __float_as_uint(v);
    unsigned rh = u + 0x7FFFu + ((u >> 16) & 1u);
    h = (ushort_t)(rh >> 16);
    float hf = __uint_as_float((unsigned)h << 16);
    float rem = v - hf;
    unsigned u2 = __float_as_uint(rem);
    unsigned rl = u2 + 0x7FFFu + ((u2 >> 16) & 1u);
    l = (ushort_t)(rl >> 16);
}

// B [K][N] fp32 -> Bt_hi/Bt_lo [NP][KP] bf16 (transposed, zero-padded)
__global__ __launch_bounds__(256) void transpose_split(const float* __restrict__ B,
                                                       ushort_t* __restrict__ th,
                                                       ushort_t* __restrict__ tl,
                                                       int K, int N, int KP, int NP) {
    int idx = blockIdx.x * 256 + threadIdx.x;
    if (idx >= NP * KP) return;
    int n = idx / KP;
    int k = idx - n * KP;
    float v = (n < N && k < K) ? B[(size_t)k * N + n] : 0.f;
    ushort_t h, l;
    split1(v, h, l);
    th[idx] = h;
    tl[idx] = l;
}

// ---------------- split-bf16 MFMA GEMM ----------------
// C[M x NP] = A[M x K] @ B, with B pre-transposed/split as Bt_hi/Bt_lo [NP][K] bf16.
// Tile 64x64, BK=32, 256 threads = 4 waves, each wave a 32x32 quadrant.
// K % 32 == 0 and NP % 64 == 0 required (arranged via padding).

template <bool BIAS>
__global__ __launch_bounds__(256) void gemm_mfma(const float* __restrict__ A,
                                                 const ushort_t* __restrict__ Bth,
                                                 const ushort_t* __restrict__ Btl,
                                                 const float* __restrict__ bias,
                                                 float* __restrict__ C,
                                                 int M, int K, int CS) {
    constexpr int SK = 40;  // padded LDS stride (bf16 elems): gcd(20,32)=4 -> <=2-way conflicts
    __shared__ ushort_t Ah[64 * SK], Al[64 * SK], Bh[64 * SK], Bl[64 * SK];
    const int t    = threadIdx.x;
    const int lane = t & 63;
    const int wave = t >> 6;
    const int quad = lane >> 4;
    const int l16  = lane & 15;
    const int wm   = wave >> 1;
    const int wn   = wave & 1;
    const int bm   = blockIdx.x * 64;
    const int bn   = blockIdx.y * 64;
    const int r    = t >> 2;          // staging row 0..63
    const int kc   = (t & 3) * 8;     // staging k-chunk
    const bool arow_ok = (bm + r) < M;

    const float*    Arow  = A   + (size_t)(bm + r) * K + kc;
    const ushort_t* Bhrow = Bth + (size_t)(bn + r) * K + kc;
    const ushort_t* Blrow = Btl + (size_t)(bn + r) * K + kc;

    v4f acc[2][2];
    #pragma unroll
    for (int i = 0; i < 2; ++i)
        #pragma unroll
        for (int j = 0; j < 2; ++j) acc[i][j] = 0.f;

    for (int k0 = 0; k0 < K; k0 += 32) {
        if (k0) __syncthreads();
        // stage A (fp32 -> hi/lo bf16)
        {
            float va[8];
            if (arow_ok) {
                float4 p = *(const float4*)(Arow + k0);
                float4 q = *(const float4*)(Arow + k0 + 4);
                va[0] = p.x; va[1] = p.y; va[2] = p.z; va[3] = p.w;
                va[4] = q.x; va[5] = q.y; va[6] = q.z; va[7] = q.w;
            } else {
                #pragma unroll
                for (int i = 0; i < 8; ++i) va[i] = 0.f;
            }
            u16x8 hv, lv;
            #pragma unroll
            for (int i = 0; i < 8; ++i) {
                ushort_t h, l;
                split1(va[i], h, l);
                hv[i] = h;
                lv[i] = l;
            }
            *(u16x8*)&Ah[r * SK + kc] = hv;
            *(u16x8*)&Al[r * SK + kc] = lv;
        }
        // stage B (already bf16 hi/lo, transposed)
        *(u16x8*)&Bh[r * SK + kc] = *(const u16x8*)(Bhrow + k0);
        *(u16x8*)&Bl[r * SK + kc] = *(const u16x8*)(Blrow + k0);
        __syncthreads();

        v8s ah[2], al2[2], bh2[2], bl2[2];
        #pragma unroll
        for (int tt = 0; tt < 2; ++tt) {
            int ma = (wm * 32 + tt * 16 + l16) * SK + quad * 8;
            ah[tt]  = *(const v8s*)&Ah[ma];
            al2[tt] = *(const v8s*)&Al[ma];
            int nb = (wn * 32 + tt * 16 + l16) * SK + quad * 8;
            bh2[tt] = *(const v8s*)&Bh[nb];
            bl2[tt] = *(const v8s*)&Bl[nb];
        }
        #pragma unroll
        for (int tm = 0; tm < 2; ++tm)
            #pragma unroll
            for (int tn = 0; tn < 2; ++tn) {
                acc[tm][tn] = __builtin_amdgcn_mfma_f32_16x16x32_bf16(
                    ah[tm], bh2[tn], acc[tm][tn], 0, 0, 0);
                acc[tm][tn] = __builtin_amdgcn_mfma_f32_16x16x32_bf16(
                    ah[tm], bl2[tn], acc[tm][tn], 0, 0, 0);
                acc[tm][tn] = __builtin_amdgcn_mfma_f32_16x16x32_bf16(
                    al2[tm], bh2[tn], acc[tm][tn], 0, 0, 0);
            }
    }

    // epilogue: C/D layout col=lane&15, row=quad*4+reg
    #pragma unroll
    for (int tm = 0; tm < 2; ++tm) {
        #pragma unroll
        for (int tn = 0; tn < 2; ++tn) {
            int row0 = bm + wm * 32 + tm * 16 + quad * 4;
            int col  = bn + wn * 32 + tn * 16 + l16;
            float badd = BIAS ? bias[col] : 0.f;
            #pragma unroll
            for (int reg = 0; reg < 4; ++reg) {
                int row = row0 + reg;
                if (row < M) C[(size_t)row * CS + col] = acc[tm][tn][reg] + badd;
            }
        }
    }
}

// ---------------- attention coefficients: asrc/adst [N, NH] ----------------

template <int C, int S>
__global__ __launch_bounds__(256) void att_kernel(const float* __restrict__ hpre,
                                                  const float* __restrict__ a_src,
                                                  const float* __restrict__ a_dst,
                                                  float* __restrict__ asrc,
                                                  float* __restrict__ adst, int n) {
    int idx = blockIdx.x * blockDim.x + threadIdx.x;
    if (idx >= n * NH) return;
    int node = idx >> 3, h = idx & 7;
    const float* row = hpre + (size_t)node * S + h * C;
    float s1 = 0.f, s2 = 0.f;
    #pragma unroll 4
    for (int i = 0; i < C; ++i) {
        float v = row[i];
        s1 += v * a_src[h * C + i];
        s2 += v * a_dst[h * C + i];
    }
    asrc[idx] = s1;
    adst[idx] = s2;
}

// ---------------- fused single-pass softmax aggregation ----------------
// SPLIT waves per dst node; RS = row stride in floats (may exceed HC for padded bufs).

template <int C, int HC, int RS, int SPLIT, bool ELU, bool PADW>
__global__ __launch_bounds__(256) void agg_kernel(const float* __restrict__ hpre,
                                                  const float* __restrict__ asrc,
                                                  const float* __restrict__ adst,
                                                  const int* __restrict__ row_start,
                                                  const int* __restrict__ edge_src,
                                                  const float* __restrict__ bias,
                                                  float* __restrict__ out,
                                                  int n) {
    constexpr int NQ = HC / 4;
    const int gw   = (blockIdx.x * blockDim.x + threadIdx.x) >> 6;
    const int lane = threadIdx.x & 63;
    const int d    = gw / SPLIT;
    const int part = gw % SPLIT;
    if (d >= n) return;

    const int c4    = part * 64 + lane;
    const bool have = (c4 < NQ);
    const int c4c   = have ? c4 : 0;
    int hq[4];
    #pragma unroll
    for (int q = 0; q < 4; ++q) hq[q] = (4 * c4c + q) / C;

    const int beg = row_start[d];
    const int end = row_start[d + 1];

    const float adst_h = (lane < NH) ? adst[d * NH + lane] : 0.f;

    float m, s;
    float4 acc;
    {
        float a = (lane < NH) ? asrc[d * NH + lane] + adst_h : 0.f;
        a = fmaxf(a, 0.2f * a);
        m = a;
        s = 1.f;
        const float4* row = (const float4*)(hpre + (size_t)d * RS);
        acc = have ? row[c4] : make_float4(0.f, 0.f, 0.f, 0.f);
    }

    int e = beg;
    for (; e + 1 < end; e += 2) {
        int s1 = edge_src[e];
        int s2 = edge_src[e + 1];
        const float4* r1 = (const float4*)(hpre + (size_t)s1 * RS);
        const float4* r2 = (const float4*)(hpre + (size_t)s2 * RS);
        float4 v1 = have ? r1[c4] : make_float4(0.f, 0.f, 0.f, 0.f);
        float4 v2 = have ? r2[c4] : make_float4(0.f, 0.f, 0.f, 0.f);
        float a1 = 0.f, a2 = 0.f;
        if (lane < NH) {
            a1 = asrc[s1 * NH + lane] + adst_h;
            a2 = asrc[s2 * NH + lane] + adst_h;
        }
        a1 = fmaxf(a1, 0.2f * a1);
        a2 = fmaxf(a2, 0.2f * a2);
        float mn = fmaxf(m, fmaxf(a1, a2));
        float al = __expf(m - mn);
        float w1 = __expf(a1 - mn);
        float w2 = __expf(a2 - mn);
        s = s * al + w1 + w2;
        m = mn;
        if constexpr (C == 64) {
            int h = c4c >> 4;
            float alc = __shfl(al, h);
            float w1c = __shfl(w1, h);
            float w2c = __shfl(w2, h);
            acc.x = acc.x * alc + w1c * v1.x + w2c * v2.x;
            acc.y = acc.y * alc + w1c * v1.y + w2c * v2.y;
            acc.z = acc.z * alc + w1c * v1.z + w2c * v2.z;
            acc.w = acc.w * alc + w1c * v1.w + w2c * v2.w;
        } else {
            acc.x = acc.x * __shfl(al, hq[0]) + __shfl(w1, hq[0]) * v1.x + __shfl(w2, hq[0]) * v2.x;
            acc.y = acc.y * __shfl(al, hq[1]) + __shfl(w1, hq[1]) * v1.y + __shfl(w2, hq[1]) * v2.y;
            acc.z = acc.z * __shfl(al, hq[2]) + __shfl(w1, hq[2]) * v1.z + __shfl(w2, hq[2]) * v2.z;
            acc.w = acc.w * __shfl(al, hq[3]) + __shfl(w1, hq[3]) * v1.w + __shfl(w2, hq[3]) * v2.w;
        }
    }
    if (e < end) {
        int s1 = edge_src[e];
        const float4* r1 = (const float4*)(hpre + (size_t)s1 * RS);
        float4 v1 = have ? r1[c4] : make_float4(0.f, 0.f, 0.f, 0.f);
        float a1 = 0.f;
        if (lane < NH) a1 = asrc[s1 * NH + lane] + adst_h;
        a1 = fmaxf(a1, 0.2f * a1);
        float mn = fmaxf(m, a1);
        float al = __expf(m - mn);
        float w1 = __expf(a1 - mn);
        s = s * al + w1;
        m = mn;
        if constexpr (C == 64) {
            int h = c4c >> 4;
            float alc = __shfl(al, h);
            float w1c = __shfl(w1, h);
            acc.x = acc.x * alc + w1c * v1.x;
            acc.y = acc.y * alc + w1c * v1.y;
            acc.z = acc.z * alc + w1c * v1.z;
            acc.w = acc.w * alc + w1c * v1.w;
        } else {
            acc.x = acc.x * __shfl(al, hq[0]) + __shfl(w1, hq[0]) * v1.x;
            acc.y = acc.y * __shfl(al, hq[1]) + __shfl(w1, hq[1]) * v1.y;
            acc.z = acc.z * __shfl(al, hq[2]) + __shfl(w1, hq[2]) * v1.z;
            acc.w = acc.w * __shfl(al, hq[3]) + __shfl(w1, hq[3]) * v1.w;
        }
    }

    float inv = 1.f / s;
    if (have) {
        float4 b4 = ((const float4*)bias)[c4];
        float4 v;
        if constexpr (C == 64) {
            float ivc = __shfl(inv, c4c >> 4);
            v.x = acc.x * ivc + b4.x;
            v.y = acc.y * ivc + b4.y;
            v.z = acc.z * ivc + b4.z;
            v.w = acc.w * ivc + b4.w;
        } else {
            v.x = acc.x * __shfl(inv, hq[0]) + b4.x;
            v.y = acc.y * __shfl(inv, hq[1]) + b4.y;
            v.z = acc.z * __shfl(inv, hq[2]) + b4.z;
            v.w = acc.w * __shfl(inv, hq[3]) + b4.w;
        }
        if (ELU) {
            v.x = (v.x > 0.f) ? v.x : __expf(v.x) - 1.f;
            v.y = (v.y > 0.f) ? v.y : __expf(v.y) - 1.f;
            v.z = (v.z > 0.f) ? v.z : __expf(v.z) - 1.f;
            v.w = (v.w > 0.f) ? v.w : __expf(v.w) - 1.f;
        }
        ((float4*)(out + (size_t)d * RS))[c4] = v;
    } else if (PADW) {
        // keep zero pad of the output buffer (feeds padded-K GEMM)
        ((float4*)(out + (size_t)d * RS))[c4] = make_float4(0.f, 0.f, 0.f, 0.f);
    }
}

// ---------------- launch ----------------

extern "C" void kernel_launch(void* const* d_in, const int* in_sizes, int n_in,
                              void* d_out, int out_size, void* d_ws, size_t ws_size,
                              hipStream_t stream) {
    const float* x      = (const float*)d_in[0];
    const int*   eidx   = (const int*)d_in[1];   // [2, E]
    const float* W1     = (const float*)d_in[2];
    const float* a1_src = (const float*)d_in[3];
    const float* a1_dst = (const float*)d_in[4];
    const float* b1     = (const float*)d_in[5];
    const float* W2     = (const float*)d_in[6];
    const float* a2_src = (const float*)d_in[7];
    const float* a2_dst = (const float*)d_in[8];
    const float* b2     = (const float*)d_in[9];
    const float* Wlin   = (const float*)d_in[10];
    const float* blin   = (const float*)d_in[11];

    const int* src = eidx;        // row 0
    const int* dst = eidx + EE;   // row 1

    float* out0  = (float*)d_out;                      // [N, NCLS]
    float* h_out = (float*)d_out + (size_t)NN * NCLS;  // [N, HC2] (output 1)

    // workspace layout: floats, then ushorts, then ints
    float* f = (float*)d_ws;
    float* h1p   = f;                         // [NN][HC1P] (zero pad cols written by GEMM)
    float* h1    = h1p + (size_t)NN * HC1P;   // [NN][HC1P] (pad zeroed by agg PADW)
    float* h2p   = h1 + (size_t)NN * HC1P;    // [NN][HC2]
    float* asrc1 = h2p + (size_t)NN * HC2;
    float* adst1 = asrc1 + NN * NH;
    float* asrc2 = adst1 + NN * NH;
    float* adst2 = asrc2 + NN * NH;
    ushort_t* w1t_h = (ushort_t*)(adst2 + NN * NH);  // [HC1P][FIN]
    ushort_t* w1t_l = w1t_h + HC1P * FIN;
    ushort_t* w2t_h = w1t_l + HC1P * FIN;            // [HC2][HC1P]
    ushort_t* w2t_l = w2t_h + HC2 * HC1P;
    ushort_t* wlt_h = w2t_l + HC2 * HC1P;            // [NCLS][HC2]
    ushort_t* wlt_l = wlt_h + NCLS * HC2;
    int* counts    = (int*)(wlt_l + NCLS * HC2);
    int* cursor    = counts + NN;
    int* row_start = cursor + NN;            // N+1
    int* edge_src  = row_start + NN + 1;     // E

    hipMemsetAsync(counts, 0, 2 * NN * sizeof(int), stream);

    // weight transposes + hi/lo split (tiny)
    transpose_split<<<(HC1P * FIN + 255) / 256, 256, 0, stream>>>(W1, w1t_h, w1t_l,
                                                                  FIN, HC1, FIN, HC1P);
    transpose_split<<<(HC2 * HC1P + 255) / 256, 256, 0, stream>>>(W2, w2t_h, w2t_l,
                                                                  HC1, HC2, HC1P, HC2);
    transpose_split<<<(NCLS * HC2 + 255) / 256, 256, 0, stream>>>(Wlin, wlt_h, wlt_l,
                                                                  HC2, NCLS, HC2, NCLS);

    // CSR by dst
    hist_kernel<<<(EE + 255) / 256, 256, 0, stream>>>(dst, counts, EE);
    scan_kernel<<<1, 256, 0, stream>>>(counts, row_start, NN);
    scatter_kernel<<<(EE + 255) / 256, 256, 0, stream>>>(src, dst, row_start, cursor,
                                                         edge_src, EE);

    const int MB = (NN + 63) / 64;  // 157

    // Layer 1: h1p[NN][256] = x @ W1 (cols 240..255 auto-zero via zero Bt rows)
    {
        dim3 grid(MB, HC1P / 64);
        gemm_mfma<false><<<grid, 256, 0, stream>>>(x, w1t_h, w1t_l, nullptr, h1p,
                                                   NN, FIN, HC1P);
    }
    att_kernel<C1, HC1P><<<(NN * NH + 255) / 256, 256, 0, stream>>>(h1p, a1_src, a1_dst,
                                                                    asrc1, adst1, NN);
    agg_kernel<C1, HC1, HC1P, 1, true, true><<<(NN + 3) / 4, 256, 0, stream>>>(
        h1p, asrc1, adst1, row_start, edge_src, b1, h1, NN);

    // Layer 2: h2p = h1[NN][256] @ W2 (K padded to 256 with zeros)
    {
        dim3 grid(MB, HC2 / 64);
        gemm_mfma<false><<<grid, 256, 0, stream>>>(h1, w2t_h, w2t_l, nullptr, h2p,
                                                   NN, HC1P, HC2);
    }
    att_kernel<C2, HC2><<<(NN * NH + 255) / 256, 256, 0, stream>>>(h2p, a2_src, a2_dst,
                                                                   asrc2, adst2, NN);
    agg_kernel<C2, HC2, HC2, 2, false, false><<<(NN * 2 + 3) / 4, 256, 0, stream>>>(
        h2p, asrc2, adst2, row_start, edge_src, b2, h_out, NN);

    // Head: out0 = h_out @ Wlin + blin
    {
        dim3 grid(MB, NCLS / 64);
        gemm_mfma<true><<<grid, 256, 0, stream>>>(h_out, wlt_h, wlt_l, blin, out0,
                                                  NN, HC2, NCLS);
    }
}

// Round 5
// 256.856 us; speedup vs baseline: 2.1291x; 1.1487x over previous
//
#include <hip/hip_runtime.h>

typedef unsigned short ushort_t;
typedef float v4f __attribute__((ext_vector_type(4)));
typedef short v8s __attribute__((ext_vector_type(8)));
typedef unsigned short u16x8 __attribute__((ext_vector_type(8)));
typedef unsigned short u16x4v __attribute__((ext_vector_type(4)));

// Problem constants
#define NN    10000
#define EE    160000
#define FIN   512
#define NH    8
#define C1    30
#define HC1   240   // NH*C1
#define HC1P  256   // padded
#define C2    64
#define HC2   512   // NH*C2
#define NCLS  64

// ---------------- CSR build ----------------

__global__ __launch_bounds__(256) void hist_kernel(const int* __restrict__ dst,
                                                   int* __restrict__ counts, int E) {
    int e = blockIdx.x * blockDim.x + threadIdx.x;
    if (e < E) atomicAdd(&counts[dst[e]], 1);
}

__global__ __launch_bounds__(256) void scan_kernel(const int* __restrict__ counts,
                                                   int* __restrict__ row_start, int n) {
    __shared__ int sums[256];
    int t = threadIdx.x;
    const int chunk = (n + 255) / 256;
    int beg = t * chunk;
    int end = min(beg + chunk, n);
    int s = 0;
    for (int i = beg; i < end && i < n; ++i) s += counts[i];
    sums[t] = s;
    __syncthreads();
    for (int off = 1; off < 256; off <<= 1) {
        int v = (t >= off) ? sums[t - off] : 0;
        __syncthreads();
        sums[t] += v;
        __syncthreads();
    }
    int run = (t == 0) ? 0 : sums[t - 1];
    for (int i = beg; i < end && i < n; ++i) {
        row_start[i] = run;
        run += counts[i];
    }
    if (t == 255) row_start[n] = sums[255];
}

__global__ __launch_bounds__(256) void scatter_kernel(const int* __restrict__ src,
                                                      const int* __restrict__ dst,
                                                      const int* __restrict__ row_start,
                                                      int* __restrict__ cursor,
                                                      int* __restrict__ edge_src, int E) {
    int e = blockIdx.x * blockDim.x + threadIdx.x;
    if (e < E) {
        int d = dst[e];
        int pos = row_start[d] + atomicAdd(&cursor[d], 1);
        edge_src[pos] = src[e];
    }
}

// ---------------- bf16 helpers ----------------

__device__ __forceinline__ void split1(float v, ushort_t& h, ushort_t& l) {
    unsigned u = __float_as_uint(v);
    unsigned rh = u + 0x7FFFu + ((u >> 16) & 1u);
    h = (ushort_t)(rh >> 16);
    float hf = __uint_as_float((unsigned)h << 16);
    float rem = v - hf;
    unsigned u2 = __float_as_uint(rem);
    unsigned rl = u2 + 0x7FFFu + ((u2 >> 16) & 1u);
    l = (ushort_t)(rl >> 16);
}

__device__ __forceinline__ ushort_t f2bf(float v) {
    unsigned u = __float_as_uint(v);
    return (ushort_t)((u + 0x7FFFu + ((u >> 16) & 1u)) >> 16);
}

__device__ __forceinline__ float4 bf4f(u16x4v u) {
    float4 r;
    r.x = __uint_as_float((unsigned)u[0] << 16);
    r.y = __uint_as_float((unsigned)u[1] << 16);
    r.z = __uint_as_float((unsigned)u[2] << 16);
    r.w = __uint_as_float((unsigned)u[3] << 16);
    return r;
}

// B [K][N] fp32 -> Bt_hi/Bt_lo [NP][KP] bf16 (transposed, zero-padded)
__global__ __launch_bounds__(256) void transpose_split(const float* __restrict__ B,
                                                       ushort_t* __restrict__ th,
                                                       ushort_t* __restrict__ tl,
                                                       int K, int N, int KP, int NP) {
    int idx = blockIdx.x * 256 + threadIdx.x;
    if (idx >= NP * KP) return;
    int n = idx / KP;
    int k = idx - n * KP;
    float v = (n < N && k < K) ? B[(size_t)k * N + n] : 0.f;
    ushort_t h, l;
    split1(v, h, l);
    th[idx] = h;
    tl[idx] = l;
}

// ---------------- split-bf16 MFMA GEMM ----------------

template <bool BIAS, bool SHADOW>
__global__ __launch_bounds__(256) void gemm_mfma(const float* __restrict__ A,
                                                 const ushort_t* __restrict__ Bth,
                                                 const ushort_t* __restrict__ Btl,
                                                 const float* __restrict__ bias,
                                                 float* __restrict__ C,
                                                 ushort_t* __restrict__ Cbf,
                                                 int M, int K, int CS) {
    constexpr int SK = 40;
    __shared__ ushort_t Ah[64 * SK], Al[64 * SK], Bh[64 * SK], Bl[64 * SK];
    const int t    = threadIdx.x;
    const int lane = t & 63;
    const int wave = t >> 6;
    const int quad = lane >> 4;
    const int l16  = lane & 15;
    const int wm   = wave >> 1;
    const int wn   = wave & 1;
    const int bm   = blockIdx.x * 64;
    const int bn   = blockIdx.y * 64;
    const int r    = t >> 2;
    const int kc   = (t & 3) * 8;
    const bool arow_ok = (bm + r) < M;

    const float*    Arow  = A   + (size_t)(bm + r) * K + kc;
    const ushort_t* Bhrow = Bth + (size_t)(bn + r) * K + kc;
    const ushort_t* Blrow = Btl + (size_t)(bn + r) * K + kc;

    v4f acc[2][2];
    #pragma unroll
    for (int i = 0; i < 2; ++i)
        #pragma unroll
        for (int j = 0; j < 2; ++j) acc[i][j] = 0.f;

    for (int k0 = 0; k0 < K; k0 += 32) {
        if (k0) __syncthreads();
        {
            float va[8];
            if (arow_ok) {
                float4 p = *(const float4*)(Arow + k0);
                float4 q = *(const float4*)(Arow + k0 + 4);
                va[0] = p.x; va[1] = p.y; va[2] = p.z; va[3] = p.w;
                va[4] = q.x; va[5] = q.y; va[6] = q.z; va[7] = q.w;
            } else {
                #pragma unroll
                for (int i = 0; i < 8; ++i) va[i] = 0.f;
            }
            u16x8 hv, lv;
            #pragma unroll
            for (int i = 0; i < 8; ++i) {
                ushort_t h, l;
                split1(va[i], h, l);
                hv[i] = h;
                lv[i] = l;
            }
            *(u16x8*)&Ah[r * SK + kc] = hv;
            *(u16x8*)&Al[r * SK + kc] = lv;
        }
        *(u16x8*)&Bh[r * SK + kc] = *(const u16x8*)(Bhrow + k0);
        *(u16x8*)&Bl[r * SK + kc] = *(const u16x8*)(Blrow + k0);
        __syncthreads();

        v8s ah[2], al2[2], bh2[2], bl2[2];
        #pragma unroll
        for (int tt = 0; tt < 2; ++tt) {
            int ma = (wm * 32 + tt * 16 + l16) * SK + quad * 8;
            ah[tt]  = *(const v8s*)&Ah[ma];
            al2[tt] = *(const v8s*)&Al[ma];
            int nb = (wn * 32 + tt * 16 + l16) * SK + quad * 8;
            bh2[tt] = *(const v8s*)&Bh[nb];
            bl2[tt] = *(const v8s*)&Bl[nb];
        }
        #pragma unroll
        for (int tm = 0; tm < 2; ++tm)
            #pragma unroll
            for (int tn = 0; tn < 2; ++tn) {
                acc[tm][tn] = __builtin_amdgcn_mfma_f32_16x16x32_bf16(
                    ah[tm], bh2[tn], acc[tm][tn], 0, 0, 0);
                acc[tm][tn] = __builtin_amdgcn_mfma_f32_16x16x32_bf16(
                    ah[tm], bl2[tn], acc[tm][tn], 0, 0, 0);
                acc[tm][tn] = __builtin_amdgcn_mfma_f32_16x16x32_bf16(
                    al2[tm], bh2[tn], acc[tm][tn], 0, 0, 0);
            }
    }

    #pragma unroll
    for (int tm = 0; tm < 2; ++tm) {
        #pragma unroll
        for (int tn = 0; tn < 2; ++tn) {
            int row0 = bm + wm * 32 + tm * 16 + quad * 4;
            int col  = bn + wn * 32 + tn * 16 + l16;
            float badd = BIAS ? bias[col] : 0.f;
            #pragma unroll
            for (int reg = 0; reg < 4; ++reg) {
                int row = row0 + reg;
                if (row < M) {
                    float v = acc[tm][tn][reg] + badd;
                    C[(size_t)row * CS + col] = v;
                    if (SHADOW) Cbf[(size_t)row * CS + col] = f2bf(v);
                }
            }
        }
    }
}

// ---------------- attention coefficients: asrc/adst [N, NH] ----------------

template <int C, int S>
__global__ __launch_bounds__(256) void att_kernel(const float* __restrict__ hpre,
                                                  const float* __restrict__ a_src,
                                                  const float* __restrict__ a_dst,
                                                  float* __restrict__ asrc,
                                                  float* __restrict__ adst, int n) {
    int idx = blockIdx.x * blockDim.x + threadIdx.x;
    if (idx >= n * NH) return;
    int node = idx >> 3, h = idx & 7;
    const float* row = hpre + (size_t)node * S + h * C;
    float s1 = 0.f, s2 = 0.f;
    #pragma unroll 4
    for (int i = 0; i < C; ++i) {
        float v = row[i];
        s1 += v * a_src[h * C + i];
        s2 += v * a_dst[h * C + i];
    }
    asrc[idx] = s1;
    adst[idx] = s2;
}

// ---------------- fused single-pass softmax aggregation, bf16 gather ----------------
// SPLIT waves per dst node; each lane owns 4 channels (ushort4 gather, fp32 acc).
// RSB: bf16 table row stride (ushorts). RSO: fp32 out row stride.

template <int C, int NQ, int RSB, int RSO, int SPLIT, bool ELU, bool PADW>
__global__ __launch_bounds__(256) void agg_bf(const ushort_t* __restrict__ hb,
                                              const float* __restrict__ asrc,
                                              const float* __restrict__ adst,
                                              const int* __restrict__ row_start,
                                              const int* __restrict__ edge_src,
                                              const float* __restrict__ bias,
                                              float* __restrict__ out,
                                              int n) {
    const int gw   = (blockIdx.x * blockDim.x + threadIdx.x) >> 6;
    const int lane = threadIdx.x & 63;
    const int d    = gw / SPLIT;
    const int part = gw % SPLIT;
    if (d >= n) return;

    const int c4    = part * 64 + lane;
    const bool have = (c4 < NQ);
    const int c4c   = have ? c4 : 0;
    int hq[4];
    #pragma unroll
    for (int q = 0; q < 4; ++q) hq[q] = (4 * c4c + q) / C;
    const int hOne = c4c / (C == 64 ? 16 : 1);  // head for C==64 fast path

    const int beg = row_start[d];
    const int end = row_start[d + 1];

    const float adst_h = (lane < NH) ? adst[d * NH + lane] : 0.f;

    // self-loop init
    float m, s;
    float4 acc;
    {
        float a = (lane < NH) ? asrc[d * NH + lane] + adst_h : 0.f;
        a = fmaxf(a, 0.2f * a);
        m = a;
        s = 1.f;
        acc = bf4f(*(const u16x4v*)(hb + (size_t)d * RSB + 4 * c4c));
        if (!have) acc = make_float4(0.f, 0.f, 0.f, 0.f);
    }

    int e = beg;
    for (; e + 3 < end; e += 4) {
        int s0 = edge_src[e], s1 = edge_src[e + 1], s2 = edge_src[e + 2], s3 = edge_src[e + 3];
        float4 v0 = bf4f(*(const u16x4v*)(hb + (size_t)s0 * RSB + 4 * c4c));
        float4 v1 = bf4f(*(const u16x4v*)(hb + (size_t)s1 * RSB + 4 * c4c));
        float4 v2 = bf4f(*(const u16x4v*)(hb + (size_t)s2 * RSB + 4 * c4c));
        float4 v3 = bf4f(*(const u16x4v*)(hb + (size_t)s3 * RSB + 4 * c4c));
        float a0 = 0.f, a1 = 0.f, a2 = 0.f, a3 = 0.f;
        if (lane < NH) {
            a0 = asrc[s0 * NH + lane] + adst_h;
            a1 = asrc[s1 * NH + lane] + adst_h;
            a2 = asrc[s2 * NH + lane] + adst_h;
            a3 = asrc[s3 * NH + lane] + adst_h;
        }
        a0 = fmaxf(a0, 0.2f * a0);
        a1 = fmaxf(a1, 0.2f * a1);
        a2 = fmaxf(a2, 0.2f * a2);
        a3 = fmaxf(a3, 0.2f * a3);
        float mn = fmaxf(m, fmaxf(fmaxf(a0, a1), fmaxf(a2, a3)));
        float al = __expf(m - mn);
        float w0 = __expf(a0 - mn);
        float w1 = __expf(a1 - mn);
        float w2 = __expf(a2 - mn);
        float w3 = __expf(a3 - mn);
        s = s * al + (w0 + w1) + (w2 + w3);
        m = mn;
        if constexpr (C == 64) {
            float alc = __shfl(al, hOne);
            float c0 = __shfl(w0, hOne);
            float c1 = __shfl(w1, hOne);
            float c2 = __shfl(w2, hOne);
            float c3 = __shfl(w3, hOne);
            acc.x = acc.x * alc + c0 * v0.x + c1 * v1.x + c2 * v2.x + c3 * v3.x;
            acc.y = acc.y * alc + c0 * v0.y + c1 * v1.y + c2 * v2.y + c3 * v3.y;
            acc.z = acc.z * alc + c0 * v0.z + c1 * v1.z + c2 * v2.z + c3 * v3.z;
            acc.w = acc.w * alc + c0 * v0.w + c1 * v1.w + c2 * v2.w + c3 * v3.w;
        } else {
            #pragma unroll
            for (int q = 0; q < 4; ++q) {
                float alc = __shfl(al, hq[q]);
                float c0 = __shfl(w0, hq[q]);
                float c1 = __shfl(w1, hq[q]);
                float c2 = __shfl(w2, hq[q]);
                float c3 = __shfl(w3, hq[q]);
                float* pa = (&acc.x) + q;
                float e0 = (&v0.x)[q], e1 = (&v1.x)[q], e2 = (&v2.x)[q], e3 = (&v3.x)[q];
                *pa = *pa * alc + c0 * e0 + c1 * e1 + c2 * e2 + c3 * e3;
            }
        }
    }
    for (; e < end; ++e) {
        int s0 = edge_src[e];
        float4 v0 = bf4f(*(const u16x4v*)(hb + (size_t)s0 * RSB + 4 * c4c));
        float a0 = 0.f;
        if (lane < NH) a0 = asrc[s0 * NH + lane] + adst_h;
        a0 = fmaxf(a0, 0.2f * a0);
        float mn = fmaxf(m, a0);
        float al = __expf(m - mn);
        float w0 = __expf(a0 - mn);
        s = s * al + w0;
        m = mn;
        if constexpr (C == 64) {
            float alc = __shfl(al, hOne);
            float c0 = __shfl(w0, hOne);
            acc.x = acc.x * alc + c0 * v0.x;
            acc.y = acc.y * alc + c0 * v0.y;
            acc.z = acc.z * alc + c0 * v0.z;
            acc.w = acc.w * alc + c0 * v0.w;
        } else {
            #pragma unroll
            for (int q = 0; q < 4; ++q) {
                float alc = __shfl(al, hq[q]);
                float c0 = __shfl(w0, hq[q]);
                float* pa = (&acc.x) + q;
                *pa = *pa * alc + c0 * (&v0.x)[q];
            }
        }
    }

    float inv = 1.f / s;
    if (have) {
        float4 b4 = ((const float4*)bias)[c4];
        float4 v;
        if constexpr (C == 64) {
            float ivc = __shfl(inv, hOne);
            v.x = acc.x * ivc + b4.x;
            v.y = acc.y * ivc + b4.y;
            v.z = acc.z * ivc + b4.z;
            v.w = acc.w * ivc + b4.w;
        } else {
            v.x = acc.x * __shfl(inv, hq[0]) + b4.x;
            v.y = acc.y * __shfl(inv, hq[1]) + b4.y;
            v.z = acc.z * __shfl(inv, hq[2]) + b4.z;
            v.w = acc.w * __shfl(inv, hq[3]) + b4.w;
        }
        if (ELU) {
            v.x = (v.x > 0.f) ? v.x : __expf(v.x) - 1.f;
            v.y = (v.y > 0.f) ? v.y : __expf(v.y) - 1.f;
            v.z = (v.z > 0.f) ? v.z : __expf(v.z) - 1.f;
            v.w = (v.w > 0.f) ? v.w : __expf(v.w) - 1.f;
        }
        ((float4*)(out + (size_t)d * RSO))[c4] = v;
    } else if (PADW && c4 < RSO / 4) {
        ((float4*)(out + (size_t)d * RSO))[c4] = make_float4(0.f, 0.f, 0.f, 0.f);
    }
}

// ---------------- launch ----------------

extern "C" void kernel_launch(void* const* d_in, const int* in_sizes, int n_in,
                              void* d_out, int out_size, void* d_ws, size_t ws_size,
                              hipStream_t stream) {
    const float* x      = (const float*)d_in[0];
    const int*   eidx   = (const int*)d_in[1];   // [2, E]
    const float* W1     = (const float*)d_in[2];
    const float* a1_src = (const float*)d_in[3];
    const float* a1_dst = (const float*)d_in[4];
    const float* b1     = (const float*)d_in[5];
    const float* W2     = (const float*)d_in[6];
    const float* a2_src = (const float*)d_in[7];
    const float* a2_dst = (const float*)d_in[8];
    const float* b2     = (const float*)d_in[9];
    const float* Wlin   = (const float*)d_in[10];
    const float* blin   = (const float*)d_in[11];

    const int* src = eidx;        // row 0
    const int* dst = eidx + EE;   // row 1

    float* out0  = (float*)d_out;                      // [N, NCLS]
    float* h_out = (float*)d_out + (size_t)NN * NCLS;  // [N, HC2] (output 1)

    // workspace layout: floats, then ushorts, then ints
    float* f = (float*)d_ws;
    float* h1p   = f;                         // [NN][HC1P]
    float* h1    = h1p + (size_t)NN * HC1P;   // [NN][HC1P] (pad zeroed by agg PADW)
    float* h2p   = h1 + (size_t)NN * HC1P;    // [NN][HC2]
    float* asrc1 = h2p + (size_t)NN * HC2;
    float* adst1 = asrc1 + NN * NH;
    float* asrc2 = adst1 + NN * NH;
    float* adst2 = asrc2 + NN * NH;
    ushort_t* w1t_h = (ushort_t*)(adst2 + NN * NH);  // [HC1P][FIN]
    ushort_t* w1t_l = w1t_h + HC1P * FIN;
    ushort_t* w2t_h = w1t_l + HC1P * FIN;            // [HC2][HC1P]
    ushort_t* w2t_l = w2t_h + HC2 * HC1P;
    ushort_t* wlt_h = w2t_l + HC2 * HC1P;            // [NCLS][HC2]
    ushort_t* wlt_l = wlt_h + NCLS * HC2;
    ushort_t* h1p_bf = wlt_l + NCLS * HC2;           // [NN][HC1P] bf16 shadow
    ushort_t* h2p_bf = h1p_bf + (size_t)NN * HC1P;   // [NN][HC2] bf16 shadow
    int* counts    = (int*)(h2p_bf + (size_t)NN * HC2);
    int* cursor    = counts + NN;
    int* row_start = cursor + NN;            // N+1
    int* edge_src  = row_start + NN + 1;     // E

    hipMemsetAsync(counts, 0, 2 * NN * sizeof(int), stream);

    // weight transposes + hi/lo split (tiny)
    transpose_split<<<(HC1P * FIN + 255) / 256, 256, 0, stream>>>(W1, w1t_h, w1t_l,
                                                                  FIN, HC1, FIN, HC1P);
    transpose_split<<<(HC2 * HC1P + 255) / 256, 256, 0, stream>>>(W2, w2t_h, w2t_l,
                                                                  HC1, HC2, HC1P, HC2);
    transpose_split<<<(NCLS * HC2 + 255) / 256, 256, 0, stream>>>(Wlin, wlt_h, wlt_l,
                                                                  HC2, NCLS, HC2, NCLS);

    // CSR by dst
    hist_kernel<<<(EE + 255) / 256, 256, 0, stream>>>(dst, counts, EE);
    scan_kernel<<<1, 256, 0, stream>>>(counts, row_start, NN);
    scatter_kernel<<<(EE + 255) / 256, 256, 0, stream>>>(src, dst, row_start, cursor,
                                                         edge_src, EE);

    const int MB = (NN + 63) / 64;  // 157

    // Layer 1: h1p[NN][256] = x @ W1 (+ bf16 shadow)
    {
        dim3 grid(MB, HC1P / 64);
        gemm_mfma<false, true><<<grid, 256, 0, stream>>>(x, w1t_h, w1t_l, nullptr,
                                                         h1p, h1p_bf, NN, FIN, HC1P);
    }
    att_kernel<C1, HC1P><<<(NN * NH + 255) / 256, 256, 0, stream>>>(h1p, a1_src, a1_dst,
                                                                    asrc1, adst1, NN);
    agg_bf<C1, HC1 / 4, HC1P, HC1P, 1, true, true><<<(NN + 3) / 4, 256, 0, stream>>>(
        h1p_bf, asrc1, adst1, row_start, edge_src, b1, h1, NN);

    // Layer 2: h2p = h1[NN][256] @ W2 (+ bf16 shadow)
    {
        dim3 grid(MB, HC2 / 64);
        gemm_mfma<false, true><<<grid, 256, 0, stream>>>(h1, w2t_h, w2t_l, nullptr,
                                                         h2p, h2p_bf, NN, HC1P, HC2);
    }
    att_kernel<C2, HC2><<<(NN * NH + 255) / 256, 256, 0, stream>>>(h2p, a2_src, a2_dst,
                                                                   asrc2, adst2, NN);
    agg_bf<C2, HC2 / 4, HC2, HC2, 2, false, false><<<(NN * 2 + 3) / 4, 256, 0, stream>>>(
        h2p_bf, asrc2, adst2, row_start, edge_src, b2, h_out, NN);

    // Head: out0 = h_out @ Wlin + blin
    {
        dim3 grid(MB, NCLS / 64);
        gemm_mfma<true, false><<<grid, 256, 0, stream>>>(h_out, wlt_h, wlt_l, blin,
                                                         out0, nullptr, NN, HC2, NCLS);
    }
}

// Round 6
// 250.258 us; speedup vs baseline: 2.1852x; 1.0264x over previous
//
#include <hip/hip_runtime.h>

typedef unsigned short ushort_t;
typedef float v4f __attribute__((ext_vector_type(4)));
typedef short v8s __attribute__((ext_vector_type(8)));
typedef unsigned short u16x8 __attribute__((ext_vector_type(8)));
typedef unsigned short u16x4v __attribute__((ext_vector_type(4)));

// Problem constants
#define NN    10000
#define EE    160000
#define FIN   512
#define NH    8
#define C1    30
#define HC1   240   // NH*C1
#define HC1P  256   // padded
#define C2    64
#define HC2   512   // NH*C2
#define NCLS  64

// ---------------- CSR build ----------------

__global__ __launch_bounds__(256) void hist_kernel(const int* __restrict__ dst,
                                                   int* __restrict__ counts, int E) {
    int e = blockIdx.x * blockDim.x + threadIdx.x;
    if (e < E) atomicAdd(&counts[dst[e]], 1);
}

__global__ __launch_bounds__(256) void scan_kernel(const int* __restrict__ counts,
                                                   int* __restrict__ row_start, int n) {
    __shared__ int sums[256];
    int t = threadIdx.x;
    const int chunk = (n + 255) / 256;
    int beg = t * chunk;
    int end = min(beg + chunk, n);
    int s = 0;
    for (int i = beg; i < end && i < n; ++i) s += counts[i];
    sums[t] = s;
    __syncthreads();
    for (int off = 1; off < 256; off <<= 1) {
        int v = (t >= off) ? sums[t - off] : 0;
        __syncthreads();
        sums[t] += v;
        __syncthreads();
    }
    int run = (t == 0) ? 0 : sums[t - 1];
    for (int i = beg; i < end && i < n; ++i) {
        row_start[i] = run;
        run += counts[i];
    }
    if (t == 255) row_start[n] = sums[255];
}

__global__ __launch_bounds__(256) void scatter_kernel(const int* __restrict__ src,
                                                      const int* __restrict__ dst,
                                                      const int* __restrict__ row_start,
                                                      int* __restrict__ cursor,
                                                      int* __restrict__ edge_src, int E) {
    int e = blockIdx.x * blockDim.x + threadIdx.x;
    if (e < E) {
        int d = dst[e];
        int pos = row_start[d] + atomicAdd(&cursor[d], 1);
        edge_src[pos] = src[e];
    }
}

// ---------------- bf16 helpers ----------------

__device__ __forceinline__ void split1(float v, ushort_t& h, ushort_t& l) {
    unsigned u = __float_as_uint(v);
    unsigned rh = u + 0x7FFFu + ((u >> 16) & 1u);
    h = (ushort_t)(rh >> 16);
    float hf = __uint_as_float((unsigned)h << 16);
    float rem = v - hf;
    unsigned u2 = __float_as_uint(rem);
    unsigned rl = u2 + 0x7FFFu + ((u2 >> 16) & 1u);
    l = (ushort_t)(rl >> 16);
}

__device__ __forceinline__ ushort_t f2bf(float v) {
    unsigned u = __float_as_uint(v);
    return (ushort_t)((u + 0x7FFFu + ((u >> 16) & 1u)) >> 16);
}

__device__ __forceinline__ float bf2f(ushort_t u) {
    return __uint_as_float((unsigned)u << 16);
}

__device__ __forceinline__ float4 bf4f(u16x4v u) {
    float4 r;
    r.x = bf2f(u[0]); r.y = bf2f(u[1]); r.z = bf2f(u[2]); r.w = bf2f(u[3]);
    return r;
}

// ---------------- merged weight transpose+split (one launch) ----------------

__device__ __forceinline__ void tsplit_one(const float* B, ushort_t* th, ushort_t* tl,
                                           int idx, int K, int N, int KP) {
    int n = idx / KP;
    int k = idx - n * KP;
    float v = (n < N && k < K) ? B[(size_t)k * N + n] : 0.f;
    ushort_t h, l;
    split1(v, h, l);
    th[idx] = h;
    tl[idx] = l;
}

#define TS1 (HC1P * FIN)
#define TS2 (HC2 * HC1P)
#define TS3 (NCLS * HC2)

__global__ __launch_bounds__(256) void transpose_split_all(
    const float* __restrict__ W1, const float* __restrict__ W2,
    const float* __restrict__ Wl,
    ushort_t* __restrict__ t1h, ushort_t* __restrict__ t1l,
    ushort_t* __restrict__ t2h, ushort_t* __restrict__ t2l,
    ushort_t* __restrict__ t3h, ushort_t* __restrict__ t3l) {
    int idx = blockIdx.x * 256 + threadIdx.x;
    if (idx < TS1) {
        tsplit_one(W1, t1h, t1l, idx, FIN, HC1, FIN);
    } else if (idx < TS1 + TS2) {
        tsplit_one(W2, t2h, t2l, idx - TS1, HC1, HC2, HC1P);
    } else if (idx < TS1 + TS2 + TS3) {
        tsplit_one(Wl, t3h, t3l, idx - TS1 - TS2, HC2, NCLS, HC2);
    }
}

// ---------------- split-bf16 MFMA GEMM ----------------
// C[M x NP] = A[M x K] @ B; B pre-transposed/split [NP][K] bf16 hi/lo.
// Tile 64 x (32*TN), BK=32, 256 threads = 4 waves (wm x wn = 2x2),
// each wave 32 x (16*TN). K%32==0.
// ATT (TN==4 only): also emit asrc/adst per (row, head) — requires each
// grid.y block to cover exactly 2 heads of 64 cols (C2=64 layout).

template <int TN, bool BIAS, bool WF32, bool WBF, bool ATT>
__global__ __launch_bounds__(256) void gemm_mfma(const float* __restrict__ A,
                                                 const ushort_t* __restrict__ Bth,
                                                 const ushort_t* __restrict__ Btl,
                                                 const float* __restrict__ bias,
                                                 float* __restrict__ C,
                                                 ushort_t* __restrict__ Cbf,
                                                 const float* __restrict__ att_s,
                                                 const float* __restrict__ att_d,
                                                 float* __restrict__ asrc,
                                                 float* __restrict__ adst,
                                                 int M, int K, int CS) {
    constexpr int BN = 32 * TN;
    constexpr int SK = 40;  // LDS stride (shorts): 2-way conflicts max (free)
    __shared__ ushort_t Ah[64 * SK], Al[64 * SK];
    __shared__ ushort_t Bh[BN * SK], Bl[BN * SK];
    const int t    = threadIdx.x;
    const int lane = t & 63;
    const int wave = t >> 6;
    const int quad = lane >> 4;
    const int l16  = lane & 15;
    const int wm   = wave >> 1;
    const int wn   = wave & 1;
    const int bm   = blockIdx.x * 64;
    const int bn   = blockIdx.y * BN;
    const int r    = t >> 2;
    const int kc   = (t & 3) * 8;
    const bool arow_ok = (bm + r) < M;

    const float* Arow = A + (size_t)(bm + r) * K + kc;

    v4f acc[2][TN];
    #pragma unroll
    for (int i = 0; i < 2; ++i)
        #pragma unroll
        for (int j = 0; j < TN; ++j) acc[i][j] = 0.f;

    for (int k0 = 0; k0 < K; k0 += 32) {
        if (k0) __syncthreads();
        // stage A (fp32 -> hi/lo bf16): 64 rows x 4 chunks = 256
        {
            float va[8];
            if (arow_ok) {
                float4 p = *(const float4*)(Arow + k0);
                float4 q = *(const float4*)(Arow + k0 + 4);
                va[0] = p.x; va[1] = p.y; va[2] = p.z; va[3] = p.w;
                va[4] = q.x; va[5] = q.y; va[6] = q.z; va[7] = q.w;
            } else {
                #pragma unroll
                for (int i = 0; i < 8; ++i) va[i] = 0.f;
            }
            u16x8 hv, lv;
            #pragma unroll
            for (int i = 0; i < 8; ++i) {
                ushort_t h, l;
                split1(va[i], h, l);
                hv[i] = h;
                lv[i] = l;
            }
            *(u16x8*)&Ah[r * SK + kc] = hv;
            *(u16x8*)&Al[r * SK + kc] = lv;
        }
        // stage B: BN rows x 4 chunks
        #pragma unroll
        for (int idx = t; idx < BN * 4; idx += 256) {
            int row = idx >> 2;
            int kcb = (idx & 3) * 8;
            size_t go = (size_t)(bn + row) * K + k0 + kcb;
            *(u16x8*)&Bh[row * SK + kcb] = *(const u16x8*)(Bth + go);
            *(u16x8*)&Bl[row * SK + kcb] = *(const u16x8*)(Btl + go);
        }
        __syncthreads();

        v8s ah[2], al2[2], bh2[TN], bl2[TN];
        #pragma unroll
        for (int tt = 0; tt < 2; ++tt) {
            int ma = (wm * 32 + tt * 16 + l16) * SK + quad * 8;
            ah[tt]  = *(const v8s*)&Ah[ma];
            al2[tt] = *(const v8s*)&Al[ma];
        }
        #pragma unroll
        for (int tn = 0; tn < TN; ++tn) {
            int nb = (wn * 16 * TN + tn * 16 + l16) * SK + quad * 8;
            bh2[tn] = *(const v8s*)&Bh[nb];
            bl2[tn] = *(const v8s*)&Bl[nb];
        }
        #pragma unroll
        for (int tm = 0; tm < 2; ++tm)
            #pragma unroll
            for (int tn = 0; tn < TN; ++tn) {
                acc[tm][tn] = __builtin_amdgcn_mfma_f32_16x16x32_bf16(
                    ah[tm], bh2[tn], acc[tm][tn], 0, 0, 0);
                acc[tm][tn] = __builtin_amdgcn_mfma_f32_16x16x32_bf16(
                    ah[tm], bl2[tn], acc[tm][tn], 0, 0, 0);
                acc[tm][tn] = __builtin_amdgcn_mfma_f32_16x16x32_bf16(
                    al2[tm], bh2[tn], acc[tm][tn], 0, 0, 0);
            }
    }

    // epilogue: C/D layout col=lane&15, row=quad*4+reg
    #pragma unroll
    for (int tm = 0; tm < 2; ++tm) {
        #pragma unroll
        for (int tn = 0; tn < TN; ++tn) {
            int row0 = bm + wm * 32 + tm * 16 + quad * 4;
            int col  = bn + wn * 16 * TN + tn * 16 + l16;
            float badd = BIAS ? bias[col] : 0.f;
            #pragma unroll
            for (int reg = 0; reg < 4; ++reg) {
                int row = row0 + reg;
                if (row < M) {
                    float v = acc[tm][tn][reg] + badd;
                    if (WF32) C[(size_t)row * CS + col] = v;
                    if (WBF) Cbf[(size_t)row * CS + col] = f2bf(v);
                }
            }
        }
    }

    // fused attention scores (layer-2 layout: head = col/64)
    if constexpr (ATT) {
        float aS[TN], aD[TN];
        #pragma unroll
        for (int tn = 0; tn < TN; ++tn) {
            int col = bn + wn * 16 * TN + tn * 16 + l16;
            aS[tn] = att_s[col];
            aD[tn] = att_d[col];
        }
        const int head = blockIdx.y * 2 + wn;  // BN=128 -> 2 heads/block
        #pragma unroll
        for (int tm = 0; tm < 2; ++tm) {
            #pragma unroll
            for (int reg = 0; reg < 4; ++reg) {
                float ss = 0.f, sd = 0.f;
                #pragma unroll
                for (int tn = 0; tn < TN; ++tn) {
                    ss += acc[tm][tn][reg] * aS[tn];
                    sd += acc[tm][tn][reg] * aD[tn];
                }
                #pragma unroll
                for (int off = 1; off < 16; off <<= 1) {
                    ss += __shfl_xor(ss, off);
                    sd += __shfl_xor(sd, off);
                }
                if (l16 == 0) {
                    int row = bm + wm * 32 + tm * 16 + quad * 4 + reg;
                    if (row < M) {
                        asrc[row * NH + head] = ss;
                        adst[row * NH + head] = sd;
                    }
                }
            }
        }
    }
}

// ---------------- attention coefficients (layer 1 only) ----------------

template <int C, int S>
__global__ __launch_bounds__(256) void att_kernel(const float* __restrict__ hpre,
                                                  const float* __restrict__ a_src,
                                                  const float* __restrict__ a_dst,
                                                  float* __restrict__ asrc,
                                                  float* __restrict__ adst, int n) {
    int idx = blockIdx.x * blockDim.x + threadIdx.x;
    if (idx >= n * NH) return;
    int node = idx >> 3, h = idx & 7;
    const float* row = hpre + (size_t)node * S + h * C;
    float s1 = 0.f, s2 = 0.f;
    #pragma unroll 4
    for (int i = 0; i < C; ++i) {
        float v = row[i];
        s1 += v * a_src[h * C + i];
        s2 += v * a_dst[h * C + i];
    }
    asrc[idx] = s1;
    adst[idx] = s2;
}

// ---------------- layer-1 aggregation (bf16 gather, 4ch/lane) ----------------

template <int C, int NQ, int RSB, int RSO, bool ELU, bool PADW>
__global__ __launch_bounds__(256) void agg_bf(const ushort_t* __restrict__ hb,
                                              const float* __restrict__ asrc,
                                              const float* __restrict__ adst,
                                              const int* __restrict__ row_start,
                                              const int* __restrict__ edge_src,
                                              const float* __restrict__ bias,
                                              float* __restrict__ out,
                                              int n) {
    const int d    = (blockIdx.x * blockDim.x + threadIdx.x) >> 6;
    const int lane = threadIdx.x & 63;
    if (d >= n) return;

    const int c4    = lane;
    const bool have = (c4 < NQ);
    const int c4c   = have ? c4 : 0;
    int hq[4];
    #pragma unroll
    for (int q = 0; q < 4; ++q) hq[q] = (4 * c4c + q) / C;

    const int beg = row_start[d];
    const int end = row_start[d + 1];

    const float adst_h = (lane < NH) ? adst[d * NH + lane] : 0.f;

    float m, s;
    float4 acc;
    {
        float a = (lane < NH) ? asrc[d * NH + lane] + adst_h : 0.f;
        a = fmaxf(a, 0.2f * a);
        m = a;
        s = 1.f;
        acc = bf4f(*(const u16x4v*)(hb + (size_t)d * RSB + 4 * c4c));
        if (!have) acc = make_float4(0.f, 0.f, 0.f, 0.f);
    }

    int e = beg;
    for (; e + 3 < end; e += 4) {
        int s0 = edge_src[e], s1 = edge_src[e + 1], s2 = edge_src[e + 2], s3 = edge_src[e + 3];
        float4 v0 = bf4f(*(const u16x4v*)(hb + (size_t)s0 * RSB + 4 * c4c));
        float4 v1 = bf4f(*(const u16x4v*)(hb + (size_t)s1 * RSB + 4 * c4c));
        float4 v2 = bf4f(*(const u16x4v*)(hb + (size_t)s2 * RSB + 4 * c4c));
        float4 v3 = bf4f(*(const u16x4v*)(hb + (size_t)s3 * RSB + 4 * c4c));
        float a0 = 0.f, a1 = 0.f, a2 = 0.f, a3 = 0.f;
        if (lane < NH) {
            a0 = asrc[s0 * NH + lane] + adst_h;
            a1 = asrc[s1 * NH + lane] + adst_h;
            a2 = asrc[s2 * NH + lane] + adst_h;
            a3 = asrc[s3 * NH + lane] + adst_h;
        }
        a0 = fmaxf(a0, 0.2f * a0);
        a1 = fmaxf(a1, 0.2f * a1);
        a2 = fmaxf(a2, 0.2f * a2);
        a3 = fmaxf(a3, 0.2f * a3);
        float mn = fmaxf(m, fmaxf(fmaxf(a0, a1), fmaxf(a2, a3)));
        float al = __expf(m - mn);
        float w0 = __expf(a0 - mn);
        float w1 = __expf(a1 - mn);
        float w2 = __expf(a2 - mn);
        float w3 = __expf(a3 - mn);
        s = s * al + (w0 + w1) + (w2 + w3);
        m = mn;
        #pragma unroll
        for (int q = 0; q < 4; ++q) {
            float alc = __shfl(al, hq[q]);
            float c0 = __shfl(w0, hq[q]);
            float c1 = __shfl(w1, hq[q]);
            float c2 = __shfl(w2, hq[q]);
            float c3 = __shfl(w3, hq[q]);
            float* pa = (&acc.x) + q;
            *pa = *pa * alc + c0 * (&v0.x)[q] + c1 * (&v1.x)[q] + c2 * (&v2.x)[q] + c3 * (&v3.x)[q];
        }
    }
    for (; e < end; ++e) {
        int s0 = edge_src[e];
        float4 v0 = bf4f(*(const u16x4v*)(hb + (size_t)s0 * RSB + 4 * c4c));
        float a0 = 0.f;
        if (lane < NH) a0 = asrc[s0 * NH + lane] + adst_h;
        a0 = fmaxf(a0, 0.2f * a0);
        float mn = fmaxf(m, a0);
        float al = __expf(m - mn);
        float w0 = __expf(a0 - mn);
        s = s * al + w0;
        m = mn;
        #pragma unroll
        for (int q = 0; q < 4; ++q) {
            float alc = __shfl(al, hq[q]);
            float c0 = __shfl(w0, hq[q]);
            float* pa = (&acc.x) + q;
            *pa = *pa * alc + c0 * (&v0.x)[q];
        }
    }

    float inv = 1.f / s;
    if (have) {
        float4 b4 = ((const float4*)bias)[c4];
        float4 v;
        v.x = acc.x * __shfl(inv, hq[0]) + b4.x;
        v.y = acc.y * __shfl(inv, hq[1]) + b4.y;
        v.z = acc.z * __shfl(inv, hq[2]) + b4.z;
        v.w = acc.w * __shfl(inv, hq[3]) + b4.w;
        if (ELU) {
            v.x = (v.x > 0.f) ? v.x : __expf(v.x) - 1.f;
            v.y = (v.y > 0.f) ? v.y : __expf(v.y) - 1.f;
            v.z = (v.z > 0.f) ? v.z : __expf(v.z) - 1.f;
            v.w = (v.w > 0.f) ? v.w : __expf(v.w) - 1.f;
        }
        ((float4*)(out + (size_t)d * RSO))[c4] = v;
    } else if (PADW && c4 < RSO / 4) {
        ((float4*)(out + (size_t)d * RSO))[c4] = make_float4(0.f, 0.f, 0.f, 0.f);
    }
}

// ---------------- layer-2 aggregation: 1 wave/node, 8ch/lane, u16x8 gather ----

__global__ __launch_bounds__(256) void agg_bf512(const ushort_t* __restrict__ hb,
                                                 const float* __restrict__ asrc,
                                                 const float* __restrict__ adst,
                                                 const int* __restrict__ row_start,
                                                 const int* __restrict__ edge_src,
                                                 const float* __restrict__ bias,
                                                 float* __restrict__ out,
                                                 int n) {
    const int d    = (blockIdx.x * blockDim.x + threadIdx.x) >> 6;
    const int lane = threadIdx.x & 63;
    if (d >= n) return;
    const int head = lane >> 3;  // 8 lanes per head, 8 ch per lane (64ch heads)

    const int beg = row_start[d];
    const int end = row_start[d + 1];

    const float adst_h = (lane < NH) ? adst[d * NH + lane] : 0.f;

    float m, s;
    float ac[8];
    {
        float a = (lane < NH) ? asrc[d * NH + lane] + adst_h : 0.f;
        a = fmaxf(a, 0.2f * a);
        m = a;
        s = 1.f;
        u16x8 u = *(const u16x8*)(hb + (size_t)d * HC2 + 8 * lane);
        #pragma unroll
        for (int i = 0; i < 8; ++i) ac[i] = bf2f(u[i]);
    }

    int e = beg;
    for (; e + 3 < end; e += 4) {
        int s0 = edge_src[e], s1 = edge_src[e + 1], s2 = edge_src[e + 2], s3 = edge_src[e + 3];
        u16x8 u0 = *(const u16x8*)(hb + (size_t)s0 * HC2 + 8 * lane);
        u16x8 u1 = *(const u16x8*)(hb + (size_t)s1 * HC2 + 8 * lane);
        u16x8 u2 = *(const u16x8*)(hb + (size_t)s2 * HC2 + 8 * lane);
        u16x8 u3 = *(const u16x8*)(hb + (size_t)s3 * HC2 + 8 * lane);
        float a0 = 0.f, a1 = 0.f, a2 = 0.f, a3 = 0.f;
        if (lane < NH) {
            a0 = asrc[s0 * NH + lane] + adst_h;
            a1 = asrc[s1 * NH + lane] + adst_h;
            a2 = asrc[s2 * NH + lane] + adst_h;
            a3 = asrc[s3 * NH + lane] + adst_h;
        }
        a0 = fmaxf(a0, 0.2f * a0);
        a1 = fmaxf(a1, 0.2f * a1);
        a2 = fmaxf(a2, 0.2f * a2);
        a3 = fmaxf(a3, 0.2f * a3);
        float mn = fmaxf(m, fmaxf(fmaxf(a0, a1), fmaxf(a2, a3)));
        float al = __expf(m - mn);
        float w0 = __expf(a0 - mn);
        float w1 = __expf(a1 - mn);
        float w2 = __expf(a2 - mn);
        float w3 = __expf(a3 - mn);
        s = s * al + (w0 + w1) + (w2 + w3);
        m = mn;
        float alc = __shfl(al, head);
        float c0 = __shfl(w0, head);
        float c1 = __shfl(w1, head);
        float c2 = __shfl(w2, head);
        float c3 = __shfl(w3, head);
        #pragma unroll
        for (int i = 0; i < 8; ++i)
            ac[i] = ac[i] * alc + c0 * bf2f(u0[i]) + c1 * bf2f(u1[i]) +
                    c2 * bf2f(u2[i]) + c3 * bf2f(u3[i]);
    }
    for (; e < end; ++e) {
        int s0 = edge_src[e];
        u16x8 u0 = *(const u16x8*)(hb + (size_t)s0 * HC2 + 8 * lane);
        float a0 = 0.f;
        if (lane < NH) a0 = asrc[s0 * NH + lane] + adst_h;
        a0 = fmaxf(a0, 0.2f * a0);
        float mn = fmaxf(m, a0);
        float al = __expf(m - mn);
        float w0 = __expf(a0 - mn);
        s = s * al + w0;
        m = mn;
        float alc = __shfl(al, head);
        float c0 = __shfl(w0, head);
        #pragma unroll
        for (int i = 0; i < 8; ++i) ac[i] = ac[i] * alc + c0 * bf2f(u0[i]);
    }

    float inv = 1.f / s;
    float ivc = __shfl(inv, head);
    const float4* b4p = (const float4*)bias;
    float4 b0 = b4p[2 * lane], b1 = b4p[2 * lane + 1];
    float4 o0, o1;
    o0.x = ac[0] * ivc + b0.x;
    o0.y = ac[1] * ivc + b0.y;
    o0.z = ac[2] * ivc + b0.z;
    o0.w = ac[3] * ivc + b0.w;
    o1.x = ac[4] * ivc + b1.x;
    o1.y = ac[5] * ivc + b1.y;
    o1.z = ac[6] * ivc + b1.z;
    o1.w = ac[7] * ivc + b1.w;
    float4* orow = (float4*)(out + (size_t)d * HC2);
    orow[2 * lane]     = o0;
    orow[2 * lane + 1] = o1;
}

// ---------------- launch ----------------

extern "C" void kernel_launch(void* const* d_in, const int* in_sizes, int n_in,
                              void* d_out, int out_size, void* d_ws, size_t ws_size,
                              hipStream_t stream) {
    const float* x      = (const float*)d_in[0];
    const int*   eidx   = (const int*)d_in[1];   // [2, E]
    const float* W1     = (const float*)d_in[2];
    const float* a1_src = (const float*)d_in[3];
    const float* a1_dst = (const float*)d_in[4];
    const float* b1     = (const float*)d_in[5];
    const float* W2     = (const float*)d_in[6];
    const float* a2_src = (const float*)d_in[7];
    const float* a2_dst = (const float*)d_in[8];
    const float* b2     = (const float*)d_in[9];
    const float* Wlin   = (const float*)d_in[10];
    const float* blin   = (const float*)d_in[11];

    const int* src = eidx;        // row 0
    const int* dst = eidx + EE;   // row 1

    float* out0  = (float*)d_out;                      // [N, NCLS]
    float* h_out = (float*)d_out + (size_t)NN * NCLS;  // [N, HC2] (output 1)

    // workspace layout: floats, then ushorts, then ints
    float* f = (float*)d_ws;
    float* h1p   = f;                         // [NN][HC1P] fp32 (att1 input)
    float* h1    = h1p + (size_t)NN * HC1P;   // [NN][HC1P] fp32 (L2 GEMM A input)
    float* asrc1 = h1 + (size_t)NN * HC1P;
    float* adst1 = asrc1 + NN * NH;
    float* asrc2 = adst1 + NN * NH;
    float* adst2 = asrc2 + NN * NH;
    ushort_t* w1t_h = (ushort_t*)(adst2 + NN * NH);  // [HC1P][FIN]
    ushort_t* w1t_l = w1t_h + TS1;
    ushort_t* w2t_h = w1t_l + TS1;                   // [HC2][HC1P]
    ushort_t* w2t_l = w2t_h + TS2;
    ushort_t* wlt_h = w2t_l + TS2;                   // [NCLS][HC2]
    ushort_t* wlt_l = wlt_h + TS3;
    ushort_t* h1p_bf = wlt_l + TS3;                  // [NN][HC1P] bf16 shadow
    ushort_t* h2p_bf = h1p_bf + (size_t)NN * HC1P;   // [NN][HC2] bf16 shadow
    int* counts    = (int*)(h2p_bf + (size_t)NN * HC2);
    int* cursor    = counts + NN;
    int* row_start = cursor + NN;            // N+1
    int* edge_src  = row_start + NN + 1;     // E

    hipMemsetAsync(counts, 0, 2 * NN * sizeof(int), stream);

    // all weight transposes + hi/lo splits in one launch
    transpose_split_all<<<(TS1 + TS2 + TS3 + 255) / 256, 256, 0, stream>>>(
        W1, W2, Wlin, w1t_h, w1t_l, w2t_h, w2t_l, wlt_h, wlt_l);

    // CSR by dst
    hist_kernel<<<(EE + 255) / 256, 256, 0, stream>>>(dst, counts, EE);
    scan_kernel<<<1, 256, 0, stream>>>(counts, row_start, NN);
    scatter_kernel<<<(EE + 255) / 256, 256, 0, stream>>>(src, dst, row_start, cursor,
                                                         edge_src, EE);

    const int MB = (NN + 63) / 64;  // 157

    // Layer 1: h1p[NN][256] = x @ W1 (fp32 + bf16 shadow), BN=128
    {
        dim3 grid(MB, HC1P / 128);
        gemm_mfma<4, false, true, true, false><<<grid, 256, 0, stream>>>(
            x, w1t_h, w1t_l, nullptr, h1p, h1p_bf, nullptr, nullptr, nullptr, nullptr,
            NN, FIN, HC1P);
    }
    att_kernel<C1, HC1P><<<(NN * NH + 255) / 256, 256, 0, stream>>>(h1p, a1_src, a1_dst,
                                                                    asrc1, adst1, NN);
    agg_bf<C1, HC1 / 4, HC1P, HC1P, true, true><<<(NN + 3) / 4, 256, 0, stream>>>(
        h1p_bf, asrc1, adst1, row_start, edge_src, b1, h1, NN);

    // Layer 2: bf16 shadow only + fused att2 scores, BN=128 (2 heads/block)
    {
        dim3 grid(MB, HC2 / 128);
        gemm_mfma<4, false, false, true, true><<<grid, 256, 0, stream>>>(
            h1, w2t_h, w2t_l, nullptr, nullptr, h2p_bf, a2_src, a2_dst, asrc2, adst2,
            NN, HC1P, HC2);
    }
    agg_bf512<<<(NN + 3) / 4, 256, 0, stream>>>(h2p_bf, asrc2, adst2, row_start,
                                                edge_src, b2, h_out, NN);

    // Head: out0 = h_out @ Wlin + blin, BN=64
    {
        dim3 grid(MB, NCLS / 64);
        gemm_mfma<2, true, true, false, false><<<grid, 256, 0, stream>>>(
            h_out, wlt_h, wlt_l, blin, out0, nullptr, nullptr, nullptr, nullptr, nullptr,
            NN, HC2, NCLS);
    }
}